// Round 11
// baseline (271.514 us; speedup 1.0000x reference)
//
#include <hip/hip_runtime.h>

typedef __bf16 bf16x8 __attribute__((ext_vector_type(8)));
typedef __bf16 bf16x4 __attribute__((ext_vector_type(4)));
typedef float f32x4 __attribute__((ext_vector_type(4)));
typedef unsigned int u32;

__device__ __forceinline__ f32x4 mfma16(bf16x8 a, bf16x8 b, f32x4 c) {
  return __builtin_amdgcn_mfma_f32_16x16x32_bf16(a, b, c, 0, 0, 0);
}

__device__ __forceinline__ bf16x8 cvt8(float4 a, float4 b) {
  bf16x8 h;
  h[0] = (__bf16)a.x; h[1] = (__bf16)a.y; h[2] = (__bf16)a.z; h[3] = (__bf16)a.w;
  h[4] = (__bf16)b.x; h[5] = (__bf16)b.y; h[6] = (__bf16)b.z; h[7] = (__bf16)b.w;
  return h;
}

__device__ __forceinline__ void gl2lds16(const void* g, void* l) {
  __builtin_amdgcn_global_load_lds(
      (const __attribute__((address_space(1))) u32*)g,
      (__attribute__((address_space(3))) u32*)l, 16, 0, 0);
}

// Stage a 16KB tile (global rows of ROWB bytes at stride 2048B) into LDS,
// linear dest, PRE-SWIZZLED source (byte col ^= (row&7)<<4).
template<int ROWB>
__device__ __forceinline__ void stage_tile(const char* gbase, char* lbase,
                                           int w, int lane) {
  #pragma unroll
  for (int c = 0; c < 2; ++c) {
    const int o = w * 2048 + c * 1024 + lane * 16;
    const int row = o / ROWB;
    const int col = (o % ROWB) ^ ((row & 7) << 4);
    gl2lds16(gbase + (size_t)row * 2048 + col, lbase + w * 2048 + c * 1024);
  }
}

// ---------------------------------------------------------------------------
// Kernel 1: fused QKV projection (NT). Grid 1536 = 3 chunks of 512; chunk
// selects (A, W, bias, scale, out-mode) uniformly per block. Body = R9's
// proj_gemm: f32 staged raw via global_load_lds (both-sides XOR swizzle),
// bf16 convert at fragment read, one barrier per k-step, XCD map
// by=(bid&7)+8*((bid>>3)&7) (A-row-panel shares one XCD).
// Q/K out: row-major bf16 (q scaled by D^-0.5*log2e). V out: vpT [B][H][D][S']
// (S 32-block interleave: low5 4g+i(+16 hi) -> 8g+4hi+i).
// ---------------------------------------------------------------------------
__global__ __launch_bounds__(256, 2)
void proj_qkv(const float* __restrict__ query, const float* __restrict__ key,
              const float* __restrict__ value,
              const float* __restrict__ Wq, const float* __restrict__ bq,
              const float* __restrict__ Wk, const float* __restrict__ bk,
              const float* __restrict__ Wv, const float* __restrict__ bv,
              __bf16* __restrict__ qp, __bf16* __restrict__ kp,
              __bf16* __restrict__ vpT, float qscale)
{
  __shared__ __align__(16) char lds[2][32768];   // [buf][A 16KB | W 16KB]
  const int bid3 = blockIdx.x;
  const int chunk = bid3 >> 9;                   // 0=q 1=k 2=v
  const int bid = bid3 & 511;
  const float* A = chunk == 0 ? query : (chunk == 1 ? key : value);
  const float* W = chunk == 0 ? Wq : (chunk == 1 ? Wk : Wv);
  const float* bias = chunk == 0 ? bq : (chunk == 1 ? bk : bv);
  const float scale = chunk == 0 ? qscale : 1.0f;

  const int by = (bid & 7) + 8 * ((bid >> 3) & 7);  // m-tile 0..63
  const int bx = bid >> 6;                           // n-tile 0..7
  const int bm0 = by * 128, bn0 = bx * 128;
  const int tid = threadIdx.x;
  const int lane = tid & 63;
  const int w = tid >> 6;
  const int wm = (w >> 1) * 64, wn = (w & 1) * 64;
  const int lr = lane & 15, g = lane >> 4;
  const int sx = (lr & 7) << 4;

  f32x4 acc[4][4];
  #pragma unroll
  for (int i = 0; i < 4; ++i)
    #pragma unroll
    for (int j = 0; j < 4; ++j) acc[i][j] = (f32x4){0.f, 0.f, 0.f, 0.f};

  const char* Ab = (const char*)A + (size_t)bm0 * 4096;
  const char* Wb = (const char*)W + (size_t)bn0 * 4096;

  int srow[4], scol[4];
  #pragma unroll
  for (int c = 0; c < 4; ++c) {
    const int o = w * 4096 + c * 1024 + lane * 16;
    srow[c] = o >> 7;
    scol[c] = (o & 127) ^ ((srow[c] & 7) << 4);
  }

#define PJ_STAGE(buf, kk)                                                     \
  {                                                                           \
    const int kb_ = (kk) * 128;                                               \
    char* lb_ = lds[buf];                                                     \
    _Pragma("unroll")                                                         \
    for (int c = 0; c < 4; ++c) {                                             \
      gl2lds16(Ab + (size_t)srow[c] * 4096 + kb_ + scol[c],                   \
               lb_ + w * 4096 + c * 1024);                                    \
      gl2lds16(Wb + (size_t)srow[c] * 4096 + kb_ + scol[c],                   \
               lb_ + 16384 + w * 4096 + c * 1024);                            \
    }                                                                         \
  }

  PJ_STAGE(0, 0);
  __syncthreads();

  #pragma unroll 1
  for (int kk = 0; kk < 32; ++kk) {
    const int cur = kk & 1;
    if (kk < 31) PJ_STAGE(cur ^ 1, kk + 1);
    const char* la = lds[cur];
    const char* lw = lds[cur] + 16384;
    bf16x8 aF[4], bF[4];
    #pragma unroll
    for (int t = 0; t < 4; ++t) {
      const int ra = (wm + t * 16 + lr) << 7;
      const float4 a0 = *(const float4*)(la + ra + ((g * 32) ^ sx));
      const float4 a1 = *(const float4*)(la + ra + ((g * 32 + 16) ^ sx));
      aF[t] = cvt8(a0, a1);
      const int rb = (wn + t * 16 + lr) << 7;
      const float4 b0 = *(const float4*)(lw + rb + ((g * 32) ^ sx));
      const float4 b1 = *(const float4*)(lw + rb + ((g * 32 + 16) ^ sx));
      bF[t] = cvt8(b0, b1);
    }
    #pragma unroll
    for (int mt = 0; mt < 4; ++mt)
      #pragma unroll
      for (int nt = 0; nt < 4; ++nt)
        acc[mt][nt] = mfma16(aF[mt], bF[nt], acc[mt][nt]);
    __syncthreads();
  }
#undef PJ_STAGE

  const int col = lane & 15;
  const int rb = (lane >> 4) * 4;
  __bf16* Orow = chunk == 0 ? qp : kp;
  #pragma unroll
  for (int nt = 0; nt < 4; ++nt) {
    const int n = bn0 + wn + nt * 16 + col;
    const float bvv = bias[n];
    #pragma unroll
    for (int mt = 0; mt < 4; ++mt) {
      #pragma unroll
      for (int i = 0; i < 4; ++i) {
        const int m = bm0 + wm + mt * 16 + rb + i;
        const float v = (acc[mt][nt][i] + bvv) * scale;
        if (chunk < 2) {
          Orow[(size_t)m * 1024 + n] = (__bf16)v;
        } else {
          const int bb = m >> 10, s = m & 1023, hh = n >> 6, dd = n & 63;
          const int low = s & 31;
          const int si = (s & ~31) | (((low >> 2) & 3) << 3) |
                         (((low >> 4) & 1) << 2) | (low & 3);
          vpT[((size_t)((bb * 16 + hh) * 64 + dd)) * 1024 + si] = (__bf16)v;
        }
      }
    }
  }
}

// ---------------------------------------------------------------------------
// Kernel 3: out projection (R9 structure/XCD map). A bf16 (rep, 64B rows,
// swizzle (row&3)<<4), W f32 (128B rows, swizzle (row&7)<<4). f32 out.
// ---------------------------------------------------------------------------
__global__ __launch_bounds__(256, 2)
void out_gemm(const __bf16* __restrict__ A, const float* __restrict__ W,
              const float* __restrict__ bias, float* __restrict__ O)
{
  __shared__ __align__(16) char lds[2][24576];   // [buf][A 8KB | W 16KB]
  const int bid = blockIdx.x;
  const int by = (bid & 7) + 8 * ((bid >> 3) & 7);
  const int bx = bid >> 6;
  const int bm0 = by * 128, bn0 = bx * 128;
  const int tid = threadIdx.x;
  const int lane = tid & 63;
  const int w = tid >> 6;
  const int wm = (w >> 1) * 64, wn = (w & 1) * 64;
  const int lr = lane & 15, g = lane >> 4;
  const int sxA = (lr & 3) << 4;
  const int sxW = (lr & 7) << 4;

  f32x4 acc[4][4];
  #pragma unroll
  for (int i = 0; i < 4; ++i)
    #pragma unroll
    for (int j = 0; j < 4; ++j) acc[i][j] = (f32x4){0.f, 0.f, 0.f, 0.f};

  const char* Ab = (const char*)A + (size_t)bm0 * 2048;
  const char* Wb = (const char*)W + (size_t)bn0 * 4096;

  int arow[2], acol[2], wrow[4], wcol[4];
  #pragma unroll
  for (int c = 0; c < 2; ++c) {
    const int o = w * 2048 + c * 1024 + lane * 16;
    arow[c] = o >> 6;
    acol[c] = (o & 63) ^ ((arow[c] & 3) << 4);
  }
  #pragma unroll
  for (int c = 0; c < 4; ++c) {
    const int o = w * 4096 + c * 1024 + lane * 16;
    wrow[c] = o >> 7;
    wcol[c] = (o & 127) ^ ((wrow[c] & 7) << 4);
  }

#define OG_STAGE(buf, kk)                                                     \
  {                                                                           \
    char* lb_ = lds[buf];                                                     \
    _Pragma("unroll")                                                         \
    for (int c = 0; c < 2; ++c)                                               \
      gl2lds16(Ab + (size_t)arow[c] * 2048 + (kk) * 64 + acol[c],             \
               lb_ + w * 2048 + c * 1024);                                    \
    _Pragma("unroll")                                                         \
    for (int c = 0; c < 4; ++c)                                               \
      gl2lds16(Wb + (size_t)wrow[c] * 4096 + (kk) * 128 + wcol[c],            \
               lb_ + 8192 + w * 4096 + c * 1024);                             \
  }

  OG_STAGE(0, 0);
  __syncthreads();

  #pragma unroll 1
  for (int kk = 0; kk < 32; ++kk) {
    const int cur = kk & 1;
    if (kk < 31) OG_STAGE(cur ^ 1, kk + 1);
    const char* la = lds[cur];
    const char* lw = lds[cur] + 8192;
    bf16x8 aF[4], bF[4];
    #pragma unroll
    for (int t = 0; t < 4; ++t) {
      const int ra = (wm + t * 16 + lr) << 6;
      aF[t] = *(const bf16x8*)(la + ra + ((g * 16) ^ sxA));
      const int rb = (wn + t * 16 + lr) << 7;
      const float4 b0 = *(const float4*)(lw + rb + ((g * 32) ^ sxW));
      const float4 b1 = *(const float4*)(lw + rb + ((g * 32 + 16) ^ sxW));
      bF[t] = cvt8(b0, b1);
    }
    #pragma unroll
    for (int mt = 0; mt < 4; ++mt)
      #pragma unroll
      for (int nt = 0; nt < 4; ++nt)
        acc[mt][nt] = mfma16(aF[mt], bF[nt], acc[mt][nt]);
    __syncthreads();
  }
#undef OG_STAGE

  const int col = lane & 15;
  const int rb = (lane >> 4) * 4;
  #pragma unroll
  for (int nt = 0; nt < 4; ++nt) {
    const int n = bn0 + wn + nt * 16 + col;
    const float bvv = bias[n];
    #pragma unroll
    for (int mt = 0; mt < 4; ++mt) {
      #pragma unroll
      for (int i = 0; i < 4; ++i) {
        const int m = bm0 + wm + mt * 16 + rb + i;
        O[(size_t)m * 1024 + n] = acc[mt][nt][i] + bvv;
      }
    }
  }
}

// ---------------------------------------------------------------------------
// Kernel 2a: flash attention — R8 structure (128-s-tile, K16KB+V16KB dbuf,
// one barrier per tile) + fused exp/pack + log2-domain softmax with
// THR = 11.5 (= 8*log2e, same defer window as R8's e^8).
// ---------------------------------------------------------------------------
__global__ __launch_bounds__(512, 4)
void flash_attn2(const __bf16* __restrict__ qp, const __bf16* __restrict__ kp,
                 const __bf16* __restrict__ vpT, __bf16* __restrict__ rep,
                 float* __restrict__ cbuf)
{
  __shared__ __align__(16) char lds[2][32768];  // [buf][K 16KB | V 16KB]

  const int bid = blockIdx.x;
  const int b = bid & 7;
  const int rest = bid >> 3;
  const int h = rest & 15;
  const int tb = rest >> 4;
  const int tid = threadIdx.x;
  const int w = tid >> 6;
  const int lane = tid & 63;
  const int lr = lane & 15;
  const int g = lane >> 4;
  const int t0 = tb * 128 + w * 16;
  const int sx = (lr & 7) << 4;
  const int g16 = g * 16;

  const __bf16* qb = qp + (size_t)(b * 1024 + t0 + lr) * 1024 + h * 64 + g * 8;
  const bf16x8 bF0 = *(const bf16x8*)qb;
  const bf16x8 bF1 = *(const bf16x8*)(qb + 32);

  const char* kgb = (const char*)kp + ((size_t)(b * 1024) * 1024 + h * 64) * 2;
  const char* vgb = (const char*)vpT + ((size_t)((b * 16 + h) * 64) * 1024) * 2;

  f32x4 o0 = {0.f,0.f,0.f,0.f}, o1 = {0.f,0.f,0.f,0.f};
  f32x4 o2 = {0.f,0.f,0.f,0.f}, o3 = {0.f,0.f,0.f,0.f};
  float m = -3.0e38f, l = 0.f;

  stage_tile<128>(kgb, lds[0], w, lane);
  stage_tile<256>(vgb, lds[0] + 16384, w, lane);
  __syncthreads();

  #pragma unroll 1
  for (int st = 0; st < 8; ++st) {
    const char* kb = lds[st & 1];
    const char* vb = lds[st & 1] + 16384;
    if (st < 7) {
      stage_tile<128>(kgb + (size_t)(st + 1) * 128 * 2048, lds[(st & 1) ^ 1], w, lane);
      stage_tile<256>(vgb + (size_t)(st + 1) * 256, lds[(st & 1) ^ 1] + 16384, w, lane);
    }

    // ---- QK^T (swizzled LDS reads) ----
    f32x4 p[8];
    #pragma unroll
    for (int j = 0; j < 8; ++j) {
      const bf16x8 k0 = *(const bf16x8*)(kb + j * 2048 + lr * 128 + (g16 ^ sx));
      const bf16x8 k1 = *(const bf16x8*)(kb + j * 2048 + lr * 128 + ((64 + g16) ^ sx));
      f32x4 d = {0.f, 0.f, 0.f, 0.f};
      d = mfma16(k0, bF0, d);
      d = mfma16(k1, bF1, d);
      p[j] = d;
    }

    // ---- defer-max (THR = 11.5 log2-units = e^8 window) ----
    f32x4 m4 = p[0];
    #pragma unroll
    for (int j = 1; j < 8; ++j)
      #pragma unroll
      for (int i = 0; i < 4; ++i) m4[i] = fmaxf(m4[i], p[j][i]);
    const float pm = fmaxf(fmaxf(m4[0], m4[1]), fmaxf(m4[2], m4[3]));
    if (!__all(pm - m <= 11.5f)) {
      float mt = pm;
      mt = fmaxf(mt, __shfl_xor(mt, 16));
      mt = fmaxf(mt, __shfl_xor(mt, 32));
      const float mnew = fmaxf(m, mt);
      const float r = exp2f(m - mnew);
      m = mnew;
      l *= r;
      f32x4 rr;
      rr[0] = __shfl(r, g * 4 + 0);
      rr[1] = __shfl(r, g * 4 + 1);
      rr[2] = __shfl(r, g * 4 + 2);
      rr[3] = __shfl(r, g * 4 + 3);
      #pragma unroll
      for (int i = 0; i < 4; ++i) {
        o0[i] *= rr[i]; o1[i] *= rr[i]; o2[i] *= rr[i]; o3[i] *= rr[i];
      }
    }

    // ---- fused exp + sum + bf16 pack ----
    bf16x8 av[4];
    f32x4 s4 = {0.f, 0.f, 0.f, 0.f};
    #pragma unroll
    for (int j = 0; j < 8; ++j)
      #pragma unroll
      for (int i = 0; i < 4; ++i) {
        const float e = exp2f(p[j][i] - m);
        s4[i] += e;
        av[j >> 1][(j & 1) * 4 + i] = (__bf16)e;
      }
    l += (s4[0] + s4[1]) + (s4[2] + s4[3]);

    // ---- PV (interleaved vpT) ----
    #pragma unroll
    for (int m2 = 0; m2 < 4; ++m2) {
      const int vo = lr * 256 + ((m2 * 64 + g16) ^ sx);
      o0 = mfma16(av[m2], *(const bf16x8*)(vb + vo), o0);
      o1 = mfma16(av[m2], *(const bf16x8*)(vb + 4096 + vo), o1);
      o2 = mfma16(av[m2], *(const bf16x8*)(vb + 8192 + vo), o2);
      o3 = mfma16(av[m2], *(const bf16x8*)(vb + 12288 + vo), o3);
    }
    __syncthreads();
  }

  float lt = l + __shfl_xor(l, 16);
  lt += __shfl_xor(lt, 32);

  if (lane < 16) cbuf[(size_t)(b * 16 + h) * 1024 + t0 + lr] = m + log2f(lt);

  const float inv = 1.f / lt;
  f32x4 iv;
  iv[0] = __shfl(inv, g * 4 + 0);
  iv[1] = __shfl(inv, g * 4 + 1);
  iv[2] = __shfl(inv, g * 4 + 2);
  iv[3] = __shfl(inv, g * 4 + 3);
  __bf16* rbase = rep + (size_t)(b * 1024 + t0) * 1024 + h * 64 + lr;
  #pragma unroll
  for (int i = 0; i < 4; ++i) {
    const size_t ro = (size_t)(g * 4 + i) * 1024;
    rbase[ro] = (__bf16)(o0[i] * iv[i]);
    rbase[ro + 16] = (__bf16)(o1[i] * iv[i]);
    rbase[ro + 32] = (__bf16)(o2[i] * iv[i]);
    rbase[ro + 48] = (__bf16)(o3[i] * iv[i]);
  }
}

// ---------------------------------------------------------------------------
// Kernel 2b: attn_max via LSE identity, log2 domain: max_h 2^(s2_h - c_h).
// ---------------------------------------------------------------------------
__global__ __launch_bounds__(512, 4)
void amax_kernel2(const __bf16* __restrict__ qp, const __bf16* __restrict__ kp,
                  const float* __restrict__ cbuf, float* __restrict__ amax_out)
{
  __shared__ __align__(16) char lds[2][16384];

  const int bid = blockIdx.x;
  const int b = bid & 7;
  const int rest = bid >> 3;
  const int sp = rest & 7;
  const int tb = rest >> 3;
  const int tid = threadIdx.x;
  const int w = tid >> 6;
  const int lane = tid & 63;
  const int lr = lane & 15;
  const int g = lane >> 4;
  const int t0 = tb * 128 + w * 16;
  const int s0 = sp * 128;
  const int sx = (lr & 7) << 4;
  const int g16 = g * 16;

  f32x4 am[8];
  #pragma unroll
  for (int j = 0; j < 8; ++j)
    am[j] = (f32x4){-3.0e38f, -3.0e38f, -3.0e38f, -3.0e38f};

  const char* kgb = (const char*)kp + ((size_t)(b * 1024 + s0) * 1024) * 2;
  const size_t qrow = (size_t)(b * 1024 + t0 + lr) * 1024 + g * 8;

  stage_tile<128>(kgb, lds[0], w, lane);
  __syncthreads();

  #pragma unroll 1
  for (int h = 0; h < 16; ++h) {
    const char* kb = lds[h & 1];
    if (h < 15) stage_tile<128>(kgb + (h + 1) * 128, lds[(h & 1) ^ 1], w, lane);

    const __bf16* qbh = qp + qrow + h * 64;
    const bf16x8 bF0 = *(const bf16x8*)qbh;
    const bf16x8 bF1 = *(const bf16x8*)(qbh + 32);
    const float ch = cbuf[(size_t)(b * 16 + h) * 1024 + t0 + lr];

    #pragma unroll
    for (int j = 0; j < 8; ++j) {
      const bf16x8 k0 = *(const bf16x8*)(kb + j * 2048 + lr * 128 + (g16 ^ sx));
      const bf16x8 k1 = *(const bf16x8*)(kb + j * 2048 + lr * 128 + ((64 + g16) ^ sx));
      f32x4 d = {0.f, 0.f, 0.f, 0.f};
      d = mfma16(k0, bF0, d);
      d = mfma16(k1, bF1, d);
      #pragma unroll
      for (int i = 0; i < 4; ++i) am[j][i] = fmaxf(am[j][i], d[i] - ch);
    }
    __syncthreads();
  }

  const size_t arow = (size_t)(b * 1024 + t0 + lr) * 1024;
  #pragma unroll
  for (int j = 0; j < 8; ++j) {
    f32x4 v;
    #pragma unroll
    for (int i = 0; i < 4; ++i) v[i] = exp2f(am[j][i]);
    *(f32x4*)&amax_out[arow + s0 + j * 16 + g * 4] = v;
  }
}

// ---------------------------------------------------------------------------
// Fallback attention (ws too small for cbuf). log2 domain (exp2f).
// ---------------------------------------------------------------------------
__global__ __launch_bounds__(512, 4)
void attn_kernel(const __bf16* __restrict__ qp, const __bf16* __restrict__ kp,
                 const __bf16* __restrict__ vpT, __bf16* __restrict__ rep,
                 float* __restrict__ amax_out)
{
  __shared__ float2 red[16][8];
  __shared__ float invb[16];
  __shared__ __align__(16) float ob[2][8 * 64 * 17];

  const int bid = blockIdx.x;
  const int b = bid & 7;
  const int t0 = (bid >> 3) * 16;
  const int tid = threadIdx.x;
  const int lane = tid & 63;
  const int w = tid >> 6;
  const int lr = lane & 15;
  const int g = lane >> 4;

  bf16x4 am4[8];
  #pragma unroll
  for (int j = 0; j < 8; ++j)
    #pragma unroll
    for (int i = 0; i < 4; ++i) am4[j][i] = (__bf16)0.f;

  const size_t qrow = (size_t)(b * 1024 + t0 + lr) * 1024;
  const int et = tid >> 5;
  const int ed = tid & 31;

  for (int h = 0; h < 16; ++h) {
    const __bf16* qb = qp + qrow + h * 64 + g * 8;
    const bf16x8 bF0 = *(const bf16x8*)qb;
    const bf16x8 bF1 = *(const bf16x8*)(qb + 32);

    f32x4 p[8];
    #pragma unroll
    for (int j = 0; j < 8; ++j) {
      const int s0 = w * 128 + j * 16;
      const __bf16* kb = kp + (size_t)(b * 1024 + s0 + lr) * 1024 + h * 64 + g * 8;
      f32x4 d = {0.f, 0.f, 0.f, 0.f};
      d = mfma16(*(const bf16x8*)kb, bF0, d);
      d = mfma16(*(const bf16x8*)(kb + 32), bF1, d);
      p[j] = d;
    }

    f32x4 m4 = p[0];
    #pragma unroll
    for (int j = 1; j < 8; ++j)
      #pragma unroll
      for (int i = 0; i < 4; ++i) m4[i] = fmaxf(m4[i], p[j][i]);
    float mm = fmaxf(fmaxf(m4[0], m4[1]), fmaxf(m4[2], m4[3]));
    mm = fmaxf(mm, __shfl_xor(mm, 16));
    mm = fmaxf(mm, __shfl_xor(mm, 32));

    f32x4 s4 = {0.f, 0.f, 0.f, 0.f};
    #pragma unroll
    for (int j = 0; j < 8; ++j)
      #pragma unroll
      for (int i = 0; i < 4; ++i) {
        const float e = exp2f(p[j][i] - mm);
        p[j][i] = e;
        s4[i] += e;
      }
    float ss = (s4[0] + s4[1]) + (s4[2] + s4[3]);
    ss += __shfl_xor(ss, 16);
    ss += __shfl_xor(ss, 32);
    if (lane < 16) red[lr][w] = make_float2(mm, ss);
    __syncthreads();

    float m = red[lr][0].x;
    #pragma unroll
    for (int k = 1; k < 8; ++k) m = fmaxf(m, red[lr][k].x);
    float sum = 0.f;
    #pragma unroll
    for (int k = 0; k < 8; ++k) sum += red[lr][k].y * exp2f(red[lr][k].x - m);
    const float fw = exp2f(mm - m);
    const float inv = 1.f / sum;
    if (w == 0 && lane < 16) invb[lr] = inv;
    const float c = fw * inv;

    #pragma unroll
    for (int j = 0; j < 8; ++j)
      #pragma unroll
      for (int i = 0; i < 4; ++i) {
        const float pn = p[j][i] * c;
        const float o = (float)am4[j][i];
        am4[j][i] = (__bf16)fmaxf(o, pn);
      }

    f32x4 po[4];
    #pragma unroll
    for (int dc = 0; dc < 4; ++dc) po[dc] = (f32x4){0.f, 0.f, 0.f, 0.f};
    const __bf16* vb0 = vpT + ((size_t)((b * 16 + h) * 64) + lr) * 1024 + w * 128;
    #pragma unroll
    for (int m2 = 0; m2 < 4; ++m2) {
      bf16x8 av;
      #pragma unroll
      for (int i = 0; i < 4; ++i) {
        av[i] = (__bf16)(p[2 * m2][i] * fw);
        av[4 + i] = (__bf16)(p[2 * m2 + 1][i] * fw);
      }
      const int so = m2 * 32 + g * 8;
      #pragma unroll
      for (int dc = 0; dc < 4; ++dc) {
        const bf16x8 bv = *(const bf16x8*)(vb0 + (size_t)(dc * 16) * 1024 + so);
        po[dc] = mfma16(av, bv, po[dc]);
      }
    }

    float* obh = ob[h & 1];
    #pragma unroll
    for (int dc = 0; dc < 4; ++dc)
      *(f32x4*)&obh[(w * 64 + dc * 16 + lr) * 17 + g * 4] = po[dc];
    __syncthreads();

    float a0 = 0.f, a1 = 0.f;
    #pragma unroll
    for (int w2 = 0; w2 < 8; ++w2) {
      a0 += obh[(w2 * 64 + ed) * 17 + et];
      a1 += obh[(w2 * 64 + 32 + ed) * 17 + et];
    }
    const float ivv = invb[et];
    __bf16* rrow = rep + (size_t)(b * 1024 + t0 + et) * 1024 + h * 64;
    rrow[ed] = (__bf16)(a0 * ivv);
    rrow[32 + ed] = (__bf16)(a1 * ivv);
  }

  const size_t arow = (size_t)(b * 1024 + t0 + lr) * 1024;
  #pragma unroll
  for (int j = 0; j < 8; ++j) {
    f32x4 v;
    #pragma unroll
    for (int i = 0; i < 4; ++i) v[i] = (float)am4[j][i];
    *(f32x4*)&amax_out[arow + w * 128 + j * 16 + g * 4] = v;
  }
}

// ---------------------------------------------------------------------------
extern "C" void kernel_launch(void* const* d_in, const int* in_sizes, int n_in,
                              void* d_out, int out_size, void* d_ws, size_t ws_size,
                              hipStream_t stream)
{
  const float* query = (const float*)d_in[0];
  const float* key   = (const float*)d_in[1];
  const float* value = (const float*)d_in[2];
  const float* Wq = (const float*)d_in[3];
  const float* bq = (const float*)d_in[4];
  const float* Wk = (const float*)d_in[5];
  const float* bk = (const float*)d_in[6];
  const float* Wv = (const float*)d_in[7];
  const float* bv = (const float*)d_in[8];
  const float* Wo = (const float*)d_in[9];
  const float* bo = (const float*)d_in[10];

  float* out = (float*)d_out;
  float* amax_out = out + (size_t)8 * 1024 * 1024;

  char* wsb = (char*)d_ws;
  __bf16* qp  = (__bf16*)wsb;                                 // 16MB
  __bf16* kp  = (__bf16*)(wsb + ((size_t)16 << 20));          // 16MB
  __bf16* vpT = (__bf16*)(wsb + ((size_t)32 << 20));          // 16MB [B][H][D][S']

  // q scale: D^-0.5 * log2(e) -> scores in log2 domain for exp2-based softmax
  const float qscale = 0.125f * 1.44269504089f;

  proj_qkv<<<1536, 256, 0, stream>>>(query, key, value, Wq, bq, Wk, bk, Wv, bv,
                                     qp, kp, vpT, qscale);

  __bf16* rep;
  if (ws_size >= ((size_t)65 << 20)) {
    rep = (__bf16*)(wsb + ((size_t)48 << 20));                // 16MB
    float* cbuf = (float*)(wsb + ((size_t)64 << 20));         // 512KB
    flash_attn2<<<1024, 512, 0, stream>>>(qp, kp, vpT, rep, cbuf);
    amax_kernel2<<<512, 512, 0, stream>>>(qp, kp, cbuf, amax_out);
  } else {
    rep = (ws_size >= ((size_t)64 << 20)) ? (__bf16*)(wsb + ((size_t)48 << 20)) : qp;
    attn_kernel<<<512, 512, 0, stream>>>(qp, kp, vpT, rep, amax_out);
  }
  out_gemm<<<512, 256, 0, stream>>>(rep, Wo, bo, out);
}

// Round 12
// 193.145 us; speedup vs baseline: 1.4058x; 1.4058x over previous
//
#include <hip/hip_runtime.h>

typedef __bf16 bf16x8 __attribute__((ext_vector_type(8)));
typedef __bf16 bf16x4 __attribute__((ext_vector_type(4)));
typedef float f32x4 __attribute__((ext_vector_type(4)));
typedef unsigned int u32;

__device__ __forceinline__ f32x4 mfma16(bf16x8 a, bf16x8 b, f32x4 c) {
  return __builtin_amdgcn_mfma_f32_16x16x32_bf16(a, b, c, 0, 0, 0);
}

__device__ __forceinline__ bf16x8 cvt8(float4 a, float4 b) {
  bf16x8 h;
  h[0] = (__bf16)a.x; h[1] = (__bf16)a.y; h[2] = (__bf16)a.z; h[3] = (__bf16)a.w;
  h[4] = (__bf16)b.x; h[5] = (__bf16)b.y; h[6] = (__bf16)b.z; h[7] = (__bf16)b.w;
  return h;
}

__device__ __forceinline__ void gl2lds16(const void* g, void* l) {
  __builtin_amdgcn_global_load_lds(
      (const __attribute__((address_space(1))) u32*)g,
      (__attribute__((address_space(3))) u32*)l, 16, 0, 0);
}

// Stage a 16KB tile (global rows of ROWB bytes at stride 2048B) into LDS,
// linear dest, PRE-SWIZZLED source (byte col ^= (row&7)<<4).
template<int ROWB>
__device__ __forceinline__ void stage_tile(const char* gbase, char* lbase,
                                           int w, int lane) {
  #pragma unroll
  for (int c = 0; c < 2; ++c) {
    const int o = w * 2048 + c * 1024 + lane * 16;
    const int row = o / ROWB;
    const int col = (o % ROWB) ^ ((row & 7) << 4);
    gl2lds16(gbase + (size_t)row * 2048 + col, lbase + w * 2048 + c * 1024);
  }
}

// ---------------------------------------------------------------------------
// Kernel 0: f32 -> bf16 convert, all 7 tensors in one launch.
// Layout: [q 8M][k 8M][v 8M][Wq 1M][Wk 1M][Wv 1M][Wo 1M] = 29,360,128 elems;
// 8 elems/thread -> grid 14336 x 256. Segment uniform per block.
// ---------------------------------------------------------------------------
__global__ __launch_bounds__(256)
void cvt_all(const float* __restrict__ q, const float* __restrict__ k,
             const float* __restrict__ v, const float* __restrict__ wq,
             const float* __restrict__ wk, const float* __restrict__ wv,
             const float* __restrict__ wo,
             __bf16* __restrict__ qd, __bf16* __restrict__ kd,
             __bf16* __restrict__ vd, __bf16* __restrict__ wqd,
             __bf16* __restrict__ wkd, __bf16* __restrict__ wvd,
             __bf16* __restrict__ wod)
{
  const size_t gid = ((size_t)blockIdx.x * 256 + threadIdx.x) * 8;
  const float* s;
  __bf16* d;
  size_t off;
  if (gid < 8388608)           { s = q;  d = qd;  off = gid; }
  else if (gid < 16777216)     { s = k;  d = kd;  off = gid - 8388608; }
  else if (gid < 25165824)     { s = v;  d = vd;  off = gid - 16777216; }
  else {
    const size_t r = gid - 25165824;
    if (r < 1048576)           { s = wq; d = wqd; off = r; }
    else if (r < 2097152)      { s = wk; d = wkd; off = r - 1048576; }
    else if (r < 3145728)      { s = wv; d = wvd; off = r - 2097152; }
    else                       { s = wo; d = wod; off = r - 3145728; }
  }
  const float4 x0 = *(const float4*)(s + off);
  const float4 x1 = *(const float4*)(s + off + 4);
  *(bf16x8*)(d + off) = cvt8(x0, x1);
}

// ---------------------------------------------------------------------------
// Kernel 1: pure-bf16 projection GEMM (NT), BK=64. Rows in LDS are 128B ->
// exact flash staging/swizzle pattern (measured 0 bank conflicts in R10).
// 16 k-steps, one barrier each. XCD map: by=(bid&7)+8*((bid>>3)&7).
// OUT_MODE 0: row-major bf16 (scaled). OUT_MODE 1: vpT [B][H][D][S']
// (S 32-block interleave: low5 4g+i(+16 hi) -> 8g+4hi+i).
// ---------------------------------------------------------------------------
template<int OUT_MODE>
__global__ __launch_bounds__(256, 2)
void projb(const __bf16* __restrict__ A, const __bf16* __restrict__ W,
           const float* __restrict__ bias, __bf16* __restrict__ O, float scale)
{
  __shared__ __align__(16) char lds[2][32768];   // [buf][A 16KB | W 16KB]
  const int bid = blockIdx.x;
  const int by = (bid & 7) + 8 * ((bid >> 3) & 7);
  const int bx = bid >> 6;
  const int bm0 = by * 128, bn0 = bx * 128;
  const int tid = threadIdx.x;
  const int lane = tid & 63;
  const int w = tid >> 6;
  const int wm = (w >> 1) * 64, wn = (w & 1) * 64;
  const int lr = lane & 15, g = lane >> 4;
  const int sx = (lr & 7) << 4;
  const int g16 = g * 16;

  f32x4 acc[4][4];
  #pragma unroll
  for (int i = 0; i < 4; ++i)
    #pragma unroll
    for (int j = 0; j < 4; ++j) acc[i][j] = (f32x4){0.f, 0.f, 0.f, 0.f};

  const char* Ab = (const char*)A + (size_t)bm0 * 2048;
  const char* Wb = (const char*)W + (size_t)bn0 * 2048;

  int srow[4], scol[4];
  #pragma unroll
  for (int c = 0; c < 4; ++c) {
    const int o = c * 4096 + tid * 16;
    srow[c] = o >> 7;
    scol[c] = (o & 127) ^ ((srow[c] & 7) << 4);
  }

#define PB_STAGE(buf, kk)                                                     \
  {                                                                           \
    const int kb_ = (kk) * 128;                                               \
    char* lb_ = lds[buf];                                                     \
    _Pragma("unroll")                                                         \
    for (int c = 0; c < 4; ++c) {                                             \
      const int o_ = c * 4096 + tid * 16;                                     \
      gl2lds16(Ab + (size_t)srow[c] * 2048 + kb_ + scol[c], lb_ + o_);        \
      gl2lds16(Wb + (size_t)srow[c] * 2048 + kb_ + scol[c],                   \
               lb_ + 16384 + o_);                                             \
    }                                                                         \
  }

  PB_STAGE(0, 0);
  __syncthreads();

  #pragma unroll 1
  for (int kk = 0; kk < 16; ++kk) {
    const int cur = kk & 1;
    if (kk < 15) PB_STAGE(cur ^ 1, kk + 1);
    const char* la = lds[cur];
    const char* lw = lds[cur] + 16384;
    #pragma unroll
    for (int kh = 0; kh < 2; ++kh) {
      const int ko = (kh * 64 + g16) ^ sx;
      bf16x8 aF[4], bF[4];
      #pragma unroll
      for (int t = 0; t < 4; ++t) {
        aF[t] = *(const bf16x8*)(la + (wm + t * 16 + lr) * 128 + ko);
        bF[t] = *(const bf16x8*)(lw + (wn + t * 16 + lr) * 128 + ko);
      }
      #pragma unroll
      for (int mt = 0; mt < 4; ++mt)
        #pragma unroll
        for (int nt = 0; nt < 4; ++nt)
          acc[mt][nt] = mfma16(aF[mt], bF[nt], acc[mt][nt]);
    }
    __syncthreads();
  }
#undef PB_STAGE

  const int col = lane & 15;
  const int rb = (lane >> 4) * 4;
  #pragma unroll
  for (int nt = 0; nt < 4; ++nt) {
    const int n = bn0 + wn + nt * 16 + col;
    const float bvv = bias[n];
    #pragma unroll
    for (int mt = 0; mt < 4; ++mt) {
      #pragma unroll
      for (int i = 0; i < 4; ++i) {
        const int m = bm0 + wm + mt * 16 + rb + i;
        const float v = (acc[mt][nt][i] + bvv) * scale;
        if constexpr (OUT_MODE == 0) {
          O[(size_t)m * 1024 + n] = (__bf16)v;
        } else {
          const int bb = m >> 10, s = m & 1023, hh = n >> 6, dd = n & 63;
          const int low = s & 31;
          const int si = (s & ~31) | (((low >> 2) & 3) << 3) |
                         (((low >> 4) & 1) << 2) | (low & 3);
          O[((size_t)((bb * 16 + hh) * 64 + dd)) * 1024 + si] = (__bf16)v;
        }
      }
    }
  }
}

// ---------------------------------------------------------------------------
// Kernel 3: pure-bf16 out projection (rep bf16 x Wo bf16), f32 out. Same
// structure as projb.
// ---------------------------------------------------------------------------
__global__ __launch_bounds__(256, 2)
void outb(const __bf16* __restrict__ A, const __bf16* __restrict__ W,
          const float* __restrict__ bias, float* __restrict__ O)
{
  __shared__ __align__(16) char lds[2][32768];
  const int bid = blockIdx.x;
  const int by = (bid & 7) + 8 * ((bid >> 3) & 7);
  const int bx = bid >> 6;
  const int bm0 = by * 128, bn0 = bx * 128;
  const int tid = threadIdx.x;
  const int lane = tid & 63;
  const int w = tid >> 6;
  const int wm = (w >> 1) * 64, wn = (w & 1) * 64;
  const int lr = lane & 15, g = lane >> 4;
  const int sx = (lr & 7) << 4;
  const int g16 = g * 16;

  f32x4 acc[4][4];
  #pragma unroll
  for (int i = 0; i < 4; ++i)
    #pragma unroll
    for (int j = 0; j < 4; ++j) acc[i][j] = (f32x4){0.f, 0.f, 0.f, 0.f};

  const char* Ab = (const char*)A + (size_t)bm0 * 2048;
  const char* Wb = (const char*)W + (size_t)bn0 * 2048;

  int srow[4], scol[4];
  #pragma unroll
  for (int c = 0; c < 4; ++c) {
    const int o = c * 4096 + tid * 16;
    srow[c] = o >> 7;
    scol[c] = (o & 127) ^ ((srow[c] & 7) << 4);
  }

#define OB_STAGE(buf, kk)                                                     \
  {                                                                           \
    const int kb_ = (kk) * 128;                                               \
    char* lb_ = lds[buf];                                                     \
    _Pragma("unroll")                                                         \
    for (int c = 0; c < 4; ++c) {                                             \
      const int o_ = c * 4096 + tid * 16;                                     \
      gl2lds16(Ab + (size_t)srow[c] * 2048 + kb_ + scol[c], lb_ + o_);        \
      gl2lds16(Wb + (size_t)srow[c] * 2048 + kb_ + scol[c],                   \
               lb_ + 16384 + o_);                                             \
    }                                                                         \
  }

  OB_STAGE(0, 0);
  __syncthreads();

  #pragma unroll 1
  for (int kk = 0; kk < 16; ++kk) {
    const int cur = kk & 1;
    if (kk < 15) OB_STAGE(cur ^ 1, kk + 1);
    const char* la = lds[cur];
    const char* lw = lds[cur] + 16384;
    #pragma unroll
    for (int kh = 0; kh < 2; ++kh) {
      const int ko = (kh * 64 + g16) ^ sx;
      bf16x8 aF[4], bF[4];
      #pragma unroll
      for (int t = 0; t < 4; ++t) {
        aF[t] = *(const bf16x8*)(la + (wm + t * 16 + lr) * 128 + ko);
        bF[t] = *(const bf16x8*)(lw + (wn + t * 16 + lr) * 128 + ko);
      }
      #pragma unroll
      for (int mt = 0; mt < 4; ++mt)
        #pragma unroll
        for (int nt = 0; nt < 4; ++nt)
          acc[mt][nt] = mfma16(aF[mt], bF[nt], acc[mt][nt]);
    }
    __syncthreads();
  }
#undef OB_STAGE

  const int col = lane & 15;
  const int rb = (lane >> 4) * 4;
  #pragma unroll
  for (int nt = 0; nt < 4; ++nt) {
    const int n = bn0 + wn + nt * 16 + col;
    const float bvv = bias[n];
    #pragma unroll
    for (int mt = 0; mt < 4; ++mt) {
      #pragma unroll
      for (int i = 0; i < 4; ++i) {
        const int m = bm0 + wm + mt * 16 + rb + i;
        O[(size_t)m * 1024 + n] = acc[mt][nt][i] + bvv;
      }
    }
  }
}

// ---------------------------------------------------------------------------
// Fallback path kernels (ws too small for convert buffers): R9 f32-staged
// projection / out GEMMs (proven at ~42 µs each).
// ---------------------------------------------------------------------------
template<int OUT_MODE>
__global__ __launch_bounds__(256, 2)
void proj_gemm(const float* __restrict__ A, const float* __restrict__ W,
               const float* __restrict__ bias, __bf16* __restrict__ O, float scale)
{
  __shared__ __align__(16) char lds[2][32768];
  const int bid = blockIdx.x;
  const int by = (bid & 7) + 8 * ((bid >> 3) & 7);
  const int bx = bid >> 6;
  const int bm0 = by * 128, bn0 = bx * 128;
  const int tid = threadIdx.x;
  const int lane = tid & 63;
  const int w = tid >> 6;
  const int wm = (w >> 1) * 64, wn = (w & 1) * 64;
  const int lr = lane & 15, g = lane >> 4;
  const int sx = (lr & 7) << 4;

  f32x4 acc[4][4];
  #pragma unroll
  for (int i = 0; i < 4; ++i)
    #pragma unroll
    for (int j = 0; j < 4; ++j) acc[i][j] = (f32x4){0.f, 0.f, 0.f, 0.f};

  const char* Ab = (const char*)A + (size_t)bm0 * 4096;
  const char* Wb = (const char*)W + (size_t)bn0 * 4096;

  int srow[4], scol[4];
  #pragma unroll
  for (int c = 0; c < 4; ++c) {
    const int o = w * 4096 + c * 1024 + lane * 16;
    srow[c] = o >> 7;
    scol[c] = (o & 127) ^ ((srow[c] & 7) << 4);
  }

#define PJ_STAGE(buf, kk)                                                     \
  {                                                                           \
    const int kb_ = (kk) * 128;                                               \
    char* lb_ = lds[buf];                                                     \
    _Pragma("unroll")                                                         \
    for (int c = 0; c < 4; ++c) {                                             \
      gl2lds16(Ab + (size_t)srow[c] * 4096 + kb_ + scol[c],                   \
               lb_ + w * 4096 + c * 1024);                                    \
      gl2lds16(Wb + (size_t)srow[c] * 4096 + kb_ + scol[c],                   \
               lb_ + 16384 + w * 4096 + c * 1024);                            \
    }                                                                         \
  }

  PJ_STAGE(0, 0);
  __syncthreads();

  #pragma unroll 1
  for (int kk = 0; kk < 32; ++kk) {
    const int cur = kk & 1;
    if (kk < 31) PJ_STAGE(cur ^ 1, kk + 1);
    const char* la = lds[cur];
    const char* lw = lds[cur] + 16384;
    bf16x8 aF[4], bF[4];
    #pragma unroll
    for (int t = 0; t < 4; ++t) {
      const int ra = (wm + t * 16 + lr) << 7;
      const float4 a0 = *(const float4*)(la + ra + ((g * 32) ^ sx));
      const float4 a1 = *(const float4*)(la + ra + ((g * 32 + 16) ^ sx));
      aF[t] = cvt8(a0, a1);
      const int rb = (wn + t * 16 + lr) << 7;
      const float4 b0 = *(const float4*)(lw + rb + ((g * 32) ^ sx));
      const float4 b1 = *(const float4*)(lw + rb + ((g * 32 + 16) ^ sx));
      bF[t] = cvt8(b0, b1);
    }
    #pragma unroll
    for (int mt = 0; mt < 4; ++mt)
      #pragma unroll
      for (int nt = 0; nt < 4; ++nt)
        acc[mt][nt] = mfma16(aF[mt], bF[nt], acc[mt][nt]);
    __syncthreads();
  }
#undef PJ_STAGE

  const int col = lane & 15;
  const int rb = (lane >> 4) * 4;
  #pragma unroll
  for (int nt = 0; nt < 4; ++nt) {
    const int n = bn0 + wn + nt * 16 + col;
    const float bvv = bias[n];
    #pragma unroll
    for (int mt = 0; mt < 4; ++mt) {
      #pragma unroll
      for (int i = 0; i < 4; ++i) {
        const int m = bm0 + wm + mt * 16 + rb + i;
        const float v = (acc[mt][nt][i] + bvv) * scale;
        if constexpr (OUT_MODE == 0) {
          O[(size_t)m * 1024 + n] = (__bf16)v;
        } else {
          const int bb = m >> 10, s = m & 1023, hh = n >> 6, dd = n & 63;
          const int low = s & 31;
          const int si = (s & ~31) | (((low >> 2) & 3) << 3) |
                         (((low >> 4) & 1) << 2) | (low & 3);
          O[((size_t)((bb * 16 + hh) * 64 + dd)) * 1024 + si] = (__bf16)v;
        }
      }
    }
  }
}

__global__ __launch_bounds__(256, 2)
void out_gemm(const __bf16* __restrict__ A, const float* __restrict__ W,
              const float* __restrict__ bias, float* __restrict__ O)
{
  __shared__ __align__(16) char lds[2][24576];
  const int bid = blockIdx.x;
  const int by = (bid & 7) + 8 * ((bid >> 3) & 7);
  const int bx = bid >> 6;
  const int bm0 = by * 128, bn0 = bx * 128;
  const int tid = threadIdx.x;
  const int lane = tid & 63;
  const int w = tid >> 6;
  const int wm = (w >> 1) * 64, wn = (w & 1) * 64;
  const int lr = lane & 15, g = lane >> 4;
  const int sxA = (lr & 3) << 4;
  const int sxW = (lr & 7) << 4;

  f32x4 acc[4][4];
  #pragma unroll
  for (int i = 0; i < 4; ++i)
    #pragma unroll
    for (int j = 0; j < 4; ++j) acc[i][j] = (f32x4){0.f, 0.f, 0.f, 0.f};

  const char* Ab = (const char*)A + (size_t)bm0 * 2048;
  const char* Wb = (const char*)W + (size_t)bn0 * 4096;

  int arow[2], acol[2], wrow[4], wcol[4];
  #pragma unroll
  for (int c = 0; c < 2; ++c) {
    const int o = w * 2048 + c * 1024 + lane * 16;
    arow[c] = o >> 6;
    acol[c] = (o & 63) ^ ((arow[c] & 3) << 4);
  }
  #pragma unroll
  for (int c = 0; c < 4; ++c) {
    const int o = w * 4096 + c * 1024 + lane * 16;
    wrow[c] = o >> 7;
    wcol[c] = (o & 127) ^ ((wrow[c] & 7) << 4);
  }

#define OG_STAGE(buf, kk)                                                     \
  {                                                                           \
    char* lb_ = lds[buf];                                                     \
    _Pragma("unroll")                                                         \
    for (int c = 0; c < 2; ++c)                                               \
      gl2lds16(Ab + (size_t)arow[c] * 2048 + (kk) * 64 + acol[c],             \
               lb_ + w * 2048 + c * 1024);                                    \
    _Pragma("unroll")                                                         \
    for (int c = 0; c < 4; ++c)                                               \
      gl2lds16(Wb + (size_t)wrow[c] * 4096 + (kk) * 128 + wcol[c],            \
               lb_ + 8192 + w * 4096 + c * 1024);                             \
  }

  OG_STAGE(0, 0);
  __syncthreads();

  #pragma unroll 1
  for (int kk = 0; kk < 32; ++kk) {
    const int cur = kk & 1;
    if (kk < 31) OG_STAGE(cur ^ 1, kk + 1);
    const char* la = lds[cur];
    const char* lw = lds[cur] + 8192;
    bf16x8 aF[4], bF[4];
    #pragma unroll
    for (int t = 0; t < 4; ++t) {
      const int ra = (wm + t * 16 + lr) << 6;
      aF[t] = *(const bf16x8*)(la + ra + ((g * 16) ^ sxA));
      const int rb = (wn + t * 16 + lr) << 7;
      const float4 b0 = *(const float4*)(lw + rb + ((g * 32) ^ sxW));
      const float4 b1 = *(const float4*)(lw + rb + ((g * 32 + 16) ^ sxW));
      bF[t] = cvt8(b0, b1);
    }
    #pragma unroll
    for (int mt = 0; mt < 4; ++mt)
      #pragma unroll
      for (int nt = 0; nt < 4; ++nt)
        acc[mt][nt] = mfma16(aF[mt], bF[nt], acc[mt][nt]);
    __syncthreads();
  }
#undef OG_STAGE

  const int col = lane & 15;
  const int rb = (lane >> 4) * 4;
  #pragma unroll
  for (int nt = 0; nt < 4; ++nt) {
    const int n = bn0 + wn + nt * 16 + col;
    const float bvv = bias[n];
    #pragma unroll
    for (int mt = 0; mt < 4; ++mt) {
      #pragma unroll
      for (int i = 0; i < 4; ++i) {
        const int m = bm0 + wm + mt * 16 + rb + i;
        O[(size_t)m * 1024 + n] = acc[mt][nt][i] + bvv;
      }
    }
  }
}

// ---------------------------------------------------------------------------
// Kernel 2a: flash attention — R8 structure (128-s-tile, K16KB+V16KB dbuf,
// one barrier per tile) + fused exp/pack + log2-domain softmax, THR=11.5.
// ---------------------------------------------------------------------------
__global__ __launch_bounds__(512, 4)
void flash_attn2(const __bf16* __restrict__ qp, const __bf16* __restrict__ kp,
                 const __bf16* __restrict__ vpT, __bf16* __restrict__ rep,
                 float* __restrict__ cbuf)
{
  __shared__ __align__(16) char lds[2][32768];  // [buf][K 16KB | V 16KB]

  const int bid = blockIdx.x;
  const int b = bid & 7;
  const int rest = bid >> 3;
  const int h = rest & 15;
  const int tb = rest >> 4;
  const int tid = threadIdx.x;
  const int w = tid >> 6;
  const int lane = tid & 63;
  const int lr = lane & 15;
  const int g = lane >> 4;
  const int t0 = tb * 128 + w * 16;
  const int sx = (lr & 7) << 4;
  const int g16 = g * 16;

  const __bf16* qb = qp + (size_t)(b * 1024 + t0 + lr) * 1024 + h * 64 + g * 8;
  const bf16x8 bF0 = *(const bf16x8*)qb;
  const bf16x8 bF1 = *(const bf16x8*)(qb + 32);

  const char* kgb = (const char*)kp + ((size_t)(b * 1024) * 1024 + h * 64) * 2;
  const char* vgb = (const char*)vpT + ((size_t)((b * 16 + h) * 64) * 1024) * 2;

  f32x4 o0 = {0.f,0.f,0.f,0.f}, o1 = {0.f,0.f,0.f,0.f};
  f32x4 o2 = {0.f,0.f,0.f,0.f}, o3 = {0.f,0.f,0.f,0.f};
  float m = -3.0e38f, l = 0.f;

  stage_tile<128>(kgb, lds[0], w, lane);
  stage_tile<256>(vgb, lds[0] + 16384, w, lane);
  __syncthreads();

  #pragma unroll 1
  for (int st = 0; st < 8; ++st) {
    const char* kb = lds[st & 1];
    const char* vb = lds[st & 1] + 16384;
    if (st < 7) {
      stage_tile<128>(kgb + (size_t)(st + 1) * 128 * 2048, lds[(st & 1) ^ 1], w, lane);
      stage_tile<256>(vgb + (size_t)(st + 1) * 256, lds[(st & 1) ^ 1] + 16384, w, lane);
    }

    f32x4 p[8];
    #pragma unroll
    for (int j = 0; j < 8; ++j) {
      const bf16x8 k0 = *(const bf16x8*)(kb + j * 2048 + lr * 128 + (g16 ^ sx));
      const bf16x8 k1 = *(const bf16x8*)(kb + j * 2048 + lr * 128 + ((64 + g16) ^ sx));
      f32x4 d = {0.f, 0.f, 0.f, 0.f};
      d = mfma16(k0, bF0, d);
      d = mfma16(k1, bF1, d);
      p[j] = d;
    }

    f32x4 m4 = p[0];
    #pragma unroll
    for (int j = 1; j < 8; ++j)
      #pragma unroll
      for (int i = 0; i < 4; ++i) m4[i] = fmaxf(m4[i], p[j][i]);
    const float pm = fmaxf(fmaxf(m4[0], m4[1]), fmaxf(m4[2], m4[3]));
    if (!__all(pm - m <= 11.5f)) {
      float mt = pm;
      mt = fmaxf(mt, __shfl_xor(mt, 16));
      mt = fmaxf(mt, __shfl_xor(mt, 32));
      const float mnew = fmaxf(m, mt);
      const float r = exp2f(m - mnew);
      m = mnew;
      l *= r;
      f32x4 rr;
      rr[0] = __shfl(r, g * 4 + 0);
      rr[1] = __shfl(r, g * 4 + 1);
      rr[2] = __shfl(r, g * 4 + 2);
      rr[3] = __shfl(r, g * 4 + 3);
      #pragma unroll
      for (int i = 0; i < 4; ++i) {
        o0[i] *= rr[i]; o1[i] *= rr[i]; o2[i] *= rr[i]; o3[i] *= rr[i];
      }
    }

    bf16x8 av[4];
    f32x4 s4 = {0.f, 0.f, 0.f, 0.f};
    #pragma unroll
    for (int j = 0; j < 8; ++j)
      #pragma unroll
      for (int i = 0; i < 4; ++i) {
        const float e = exp2f(p[j][i] - m);
        s4[i] += e;
        av[j >> 1][(j & 1) * 4 + i] = (__bf16)e;
      }
    l += (s4[0] + s4[1]) + (s4[2] + s4[3]);

    #pragma unroll
    for (int m2 = 0; m2 < 4; ++m2) {
      const int vo = lr * 256 + ((m2 * 64 + g16) ^ sx);
      o0 = mfma16(av[m2], *(const bf16x8*)(vb + vo), o0);
      o1 = mfma16(av[m2], *(const bf16x8*)(vb + 4096 + vo), o1);
      o2 = mfma16(av[m2], *(const bf16x8*)(vb + 8192 + vo), o2);
      o3 = mfma16(av[m2], *(const bf16x8*)(vb + 12288 + vo), o3);
    }
    __syncthreads();
  }

  float lt = l + __shfl_xor(l, 16);
  lt += __shfl_xor(lt, 32);

  if (lane < 16) cbuf[(size_t)(b * 16 + h) * 1024 + t0 + lr] = m + log2f(lt);

  const float inv = 1.f / lt;
  f32x4 iv;
  iv[0] = __shfl(inv, g * 4 + 0);
  iv[1] = __shfl(inv, g * 4 + 1);
  iv[2] = __shfl(inv, g * 4 + 2);
  iv[3] = __shfl(inv, g * 4 + 3);
  __bf16* rbase = rep + (size_t)(b * 1024 + t0) * 1024 + h * 64 + lr;
  #pragma unroll
  for (int i = 0; i < 4; ++i) {
    const size_t ro = (size_t)(g * 4 + i) * 1024;
    rbase[ro] = (__bf16)(o0[i] * iv[i]);
    rbase[ro + 16] = (__bf16)(o1[i] * iv[i]);
    rbase[ro + 32] = (__bf16)(o2[i] * iv[i]);
    rbase[ro + 48] = (__bf16)(o3[i] * iv[i]);
  }
}

// ---------------------------------------------------------------------------
// Kernel 2b: attn_max via LSE identity, log2 domain: max_h 2^(s2_h - c_h).
// ---------------------------------------------------------------------------
__global__ __launch_bounds__(512, 4)
void amax_kernel2(const __bf16* __restrict__ qp, const __bf16* __restrict__ kp,
                  const float* __restrict__ cbuf, float* __restrict__ amax_out)
{
  __shared__ __align__(16) char lds[2][16384];

  const int bid = blockIdx.x;
  const int b = bid & 7;
  const int rest = bid >> 3;
  const int sp = rest & 7;
  const int tb = rest >> 3;
  const int tid = threadIdx.x;
  const int w = tid >> 6;
  const int lane = tid & 63;
  const int lr = lane & 15;
  const int g = lane >> 4;
  const int t0 = tb * 128 + w * 16;
  const int s0 = sp * 128;
  const int sx = (lr & 7) << 4;
  const int g16 = g * 16;

  f32x4 am[8];
  #pragma unroll
  for (int j = 0; j < 8; ++j)
    am[j] = (f32x4){-3.0e38f, -3.0e38f, -3.0e38f, -3.0e38f};

  const char* kgb = (const char*)kp + ((size_t)(b * 1024 + s0) * 1024) * 2;
  const size_t qrow = (size_t)(b * 1024 + t0 + lr) * 1024 + g * 8;

  stage_tile<128>(kgb, lds[0], w, lane);
  __syncthreads();

  #pragma unroll 1
  for (int h = 0; h < 16; ++h) {
    const char* kb = lds[h & 1];
    if (h < 15) stage_tile<128>(kgb + (h + 1) * 128, lds[(h & 1) ^ 1], w, lane);

    const __bf16* qbh = qp + qrow + h * 64;
    const bf16x8 bF0 = *(const bf16x8*)qbh;
    const bf16x8 bF1 = *(const bf16x8*)(qbh + 32);
    const float ch = cbuf[(size_t)(b * 16 + h) * 1024 + t0 + lr];

    #pragma unroll
    for (int j = 0; j < 8; ++j) {
      const bf16x8 k0 = *(const bf16x8*)(kb + j * 2048 + lr * 128 + (g16 ^ sx));
      const bf16x8 k1 = *(const bf16x8*)(kb + j * 2048 + lr * 128 + ((64 + g16) ^ sx));
      f32x4 d = {0.f, 0.f, 0.f, 0.f};
      d = mfma16(k0, bF0, d);
      d = mfma16(k1, bF1, d);
      #pragma unroll
      for (int i = 0; i < 4; ++i) am[j][i] = fmaxf(am[j][i], d[i] - ch);
    }
    __syncthreads();
  }

  const size_t arow = (size_t)(b * 1024 + t0 + lr) * 1024;
  #pragma unroll
  for (int j = 0; j < 8; ++j) {
    f32x4 v;
    #pragma unroll
    for (int i = 0; i < 4; ++i) v[i] = exp2f(am[j][i]);
    *(f32x4*)&amax_out[arow + s0 + j * 16 + g * 4] = v;
  }
}

// ---------------------------------------------------------------------------
// Fallback attention (ws too small for cbuf). log2 domain (exp2f).
// ---------------------------------------------------------------------------
__global__ __launch_bounds__(512, 4)
void attn_kernel(const __bf16* __restrict__ qp, const __bf16* __restrict__ kp,
                 const __bf16* __restrict__ vpT, __bf16* __restrict__ rep,
                 float* __restrict__ amax_out)
{
  __shared__ float2 red[16][8];
  __shared__ float invb[16];
  __shared__ __align__(16) float ob[2][8 * 64 * 17];

  const int bid = blockIdx.x;
  const int b = bid & 7;
  const int t0 = (bid >> 3) * 16;
  const int tid = threadIdx.x;
  const int lane = tid & 63;
  const int w = tid >> 6;
  const int lr = lane & 15;
  const int g = lane >> 4;

  bf16x4 am4[8];
  #pragma unroll
  for (int j = 0; j < 8; ++j)
    #pragma unroll
    for (int i = 0; i < 4; ++i) am4[j][i] = (__bf16)0.f;

  const size_t qrow = (size_t)(b * 1024 + t0 + lr) * 1024;
  const int et = tid >> 5;
  const int ed = tid & 31;

  for (int h = 0; h < 16; ++h) {
    const __bf16* qb = qp + qrow + h * 64 + g * 8;
    const bf16x8 bF0 = *(const bf16x8*)qb;
    const bf16x8 bF1 = *(const bf16x8*)(qb + 32);

    f32x4 p[8];
    #pragma unroll
    for (int j = 0; j < 8; ++j) {
      const int s0 = w * 128 + j * 16;
      const __bf16* kb = kp + (size_t)(b * 1024 + s0 + lr) * 1024 + h * 64 + g * 8;
      f32x4 d = {0.f, 0.f, 0.f, 0.f};
      d = mfma16(*(const bf16x8*)kb, bF0, d);
      d = mfma16(*(const bf16x8*)(kb + 32), bF1, d);
      p[j] = d;
    }

    f32x4 m4 = p[0];
    #pragma unroll
    for (int j = 1; j < 8; ++j)
      #pragma unroll
      for (int i = 0; i < 4; ++i) m4[i] = fmaxf(m4[i], p[j][i]);
    float mm = fmaxf(fmaxf(m4[0], m4[1]), fmaxf(m4[2], m4[3]));
    mm = fmaxf(mm, __shfl_xor(mm, 16));
    mm = fmaxf(mm, __shfl_xor(mm, 32));

    f32x4 s4 = {0.f, 0.f, 0.f, 0.f};
    #pragma unroll
    for (int j = 0; j < 8; ++j)
      #pragma unroll
      for (int i = 0; i < 4; ++i) {
        const float e = exp2f(p[j][i] - mm);
        p[j][i] = e;
        s4[i] += e;
      }
    float ss = (s4[0] + s4[1]) + (s4[2] + s4[3]);
    ss += __shfl_xor(ss, 16);
    ss += __shfl_xor(ss, 32);
    if (lane < 16) red[lr][w] = make_float2(mm, ss);
    __syncthreads();

    float m = red[lr][0].x;
    #pragma unroll
    for (int k = 1; k < 8; ++k) m = fmaxf(m, red[lr][k].x);
    float sum = 0.f;
    #pragma unroll
    for (int k = 0; k < 8; ++k) sum += red[lr][k].y * exp2f(red[lr][k].x - m);
    const float fw = exp2f(mm - m);
    const float inv = 1.f / sum;
    if (w == 0 && lane < 16) invb[lr] = inv;
    const float c = fw * inv;

    #pragma unroll
    for (int j = 0; j < 8; ++j)
      #pragma unroll
      for (int i = 0; i < 4; ++i) {
        const float pn = p[j][i] * c;
        const float o = (float)am4[j][i];
        am4[j][i] = (__bf16)fmaxf(o, pn);
      }

    f32x4 po[4];
    #pragma unroll
    for (int dc = 0; dc < 4; ++dc) po[dc] = (f32x4){0.f, 0.f, 0.f, 0.f};
    const __bf16* vb0 = vpT + ((size_t)((b * 16 + h) * 64) + lr) * 1024 + w * 128;
    #pragma unroll
    for (int m2 = 0; m2 < 4; ++m2) {
      bf16x8 av;
      #pragma unroll
      for (int i = 0; i < 4; ++i) {
        av[i] = (__bf16)(p[2 * m2][i] * fw);
        av[4 + i] = (__bf16)(p[2 * m2 + 1][i] * fw);
      }
      const int so = m2 * 32 + g * 8;
      #pragma unroll
      for (int dc = 0; dc < 4; ++dc) {
        const bf16x8 bv = *(const bf16x8*)(vb0 + (size_t)(dc * 16) * 1024 + so);
        po[dc] = mfma16(av, bv, po[dc]);
      }
    }

    float* obh = ob[h & 1];
    #pragma unroll
    for (int dc = 0; dc < 4; ++dc)
      *(f32x4*)&obh[(w * 64 + dc * 16 + lr) * 17 + g * 4] = po[dc];
    __syncthreads();

    float a0 = 0.f, a1 = 0.f;
    #pragma unroll
    for (int w2 = 0; w2 < 8; ++w2) {
      a0 += obh[(w2 * 64 + ed) * 17 + et];
      a1 += obh[(w2 * 64 + 32 + ed) * 17 + et];
    }
    const float ivv = invb[et];
    __bf16* rrow = rep + (size_t)(b * 1024 + t0 + et) * 1024 + h * 64;
    rrow[ed] = (__bf16)(a0 * ivv);
    rrow[32 + ed] = (__bf16)(a1 * ivv);
  }

  const size_t arow = (size_t)(b * 1024 + t0 + lr) * 1024;
  #pragma unroll
  for (int j = 0; j < 8; ++j) {
    f32x4 v;
    #pragma unroll
    for (int i = 0; i < 4; ++i) v[i] = (float)am4[j][i];
    *(f32x4*)&amax_out[arow + w * 128 + j * 16 + g * 4] = v;
  }
}

// ---------------------------------------------------------------------------
extern "C" void kernel_launch(void* const* d_in, const int* in_sizes, int n_in,
                              void* d_out, int out_size, void* d_ws, size_t ws_size,
                              hipStream_t stream)
{
  const float* query = (const float*)d_in[0];
  const float* key   = (const float*)d_in[1];
  const float* value = (const float*)d_in[2];
  const float* Wq = (const float*)d_in[3];
  const float* bq = (const float*)d_in[4];
  const float* Wk = (const float*)d_in[5];
  const float* bk = (const float*)d_in[6];
  const float* Wv = (const float*)d_in[7];
  const float* bv = (const float*)d_in[8];
  const float* Wo = (const float*)d_in[9];
  const float* bo = (const float*)d_in[10];

  float* out = (float*)d_out;
  float* amax_out = out + (size_t)8 * 1024 * 1024;

  char* wsb = (char*)d_ws;
  __bf16* qp  = (__bf16*)wsb;                                 // 16MB
  __bf16* kp  = (__bf16*)(wsb + ((size_t)16 << 20));          // 16MB
  __bf16* vpT = (__bf16*)(wsb + ((size_t)32 << 20));          // 16MB [B][H][D][S']

  // q scale: D^-0.5 * log2(e) -> scores in log2 domain for exp2-based softmax
  const float qscale = 0.125f * 1.44269504089f;

  if (ws_size >= ((size_t)105 << 20)) {
    // ---- full bf16 path: convert once, pure-bf16 GEMMs ----
    __bf16* qin = (__bf16*)(wsb + ((size_t)48 << 20));        // 16MB; reused as rep
    __bf16* kin = (__bf16*)(wsb + ((size_t)64 << 20));        // 16MB
    __bf16* vin = (__bf16*)(wsb + ((size_t)80 << 20));        // 16MB
    __bf16* Wqb = (__bf16*)(wsb + ((size_t)96 << 20));        // 2MB
    __bf16* Wkb = (__bf16*)(wsb + ((size_t)98 << 20));        // 2MB
    __bf16* Wvb = (__bf16*)(wsb + ((size_t)100 << 20));       // 2MB
    __bf16* Wob = (__bf16*)(wsb + ((size_t)102 << 20));       // 2MB
    float* cbuf = (float*)(wsb + ((size_t)104 << 20));        // 512KB
    __bf16* rep = qin;  // qin dead after proj q

    cvt_all<<<14336, 256, 0, stream>>>(query, key, value, Wq, Wk, Wv, Wo,
                                       qin, kin, vin, Wqb, Wkb, Wvb, Wob);
    projb<0><<<512, 256, 0, stream>>>(qin, Wqb, bq, qp, qscale);
    projb<0><<<512, 256, 0, stream>>>(kin, Wkb, bk, kp, 1.0f);
    projb<1><<<512, 256, 0, stream>>>(vin, Wvb, bv, vpT, 1.0f);
    flash_attn2<<<1024, 512, 0, stream>>>(qp, kp, vpT, rep, cbuf);
    amax_kernel2<<<512, 512, 0, stream>>>(qp, kp, cbuf, amax_out);
    outb<<<512, 256, 0, stream>>>(rep, Wob, bo, out);
  } else if (ws_size >= ((size_t)65 << 20)) {
    // ---- R9 f32-staged path ----
    __bf16* rep = (__bf16*)(wsb + ((size_t)48 << 20));
    float* cbuf = (float*)(wsb + ((size_t)64 << 20));
    proj_gemm<0><<<512, 256, 0, stream>>>(query, Wq, bq, qp, qscale);
    proj_gemm<0><<<512, 256, 0, stream>>>(key,   Wk, bk, kp, 1.0f);
    proj_gemm<1><<<512, 256, 0, stream>>>(value, Wv, bv, vpT, 1.0f);
    flash_attn2<<<1024, 512, 0, stream>>>(qp, kp, vpT, rep, cbuf);
    amax_kernel2<<<512, 512, 0, stream>>>(qp, kp, cbuf, amax_out);
    out_gemm<<<512, 256, 0, stream>>>(rep, Wo, bo, out);
  } else {
    __bf16* rep = (ws_size >= ((size_t)64 << 20)) ? (__bf16*)(wsb + ((size_t)48 << 20)) : qp;
    proj_gemm<0><<<512, 256, 0, stream>>>(query, Wq, bq, qp, qscale);
    proj_gemm<0><<<512, 256, 0, stream>>>(key,   Wk, bk, kp, 1.0f);
    proj_gemm<1><<<512, 256, 0, stream>>>(value, Wv, bv, vpT, 1.0f);
    attn_kernel<<<512, 512, 0, stream>>>(qp, kp, vpT, rep, amax_out);
    out_gemm<<<512, 256, 0, stream>>>(rep, Wo, bo, out);
  }
}

// Round 13
// 183.845 us; speedup vs baseline: 1.4769x; 1.0506x over previous
//
#include <hip/hip_runtime.h>

typedef __bf16 bf16x8 __attribute__((ext_vector_type(8)));
typedef __bf16 bf16x4 __attribute__((ext_vector_type(4)));
typedef float f32x4 __attribute__((ext_vector_type(4)));
typedef unsigned int u32;

__device__ __forceinline__ f32x4 mfma16(bf16x8 a, bf16x8 b, f32x4 c) {
  return __builtin_amdgcn_mfma_f32_16x16x32_bf16(a, b, c, 0, 0, 0);
}

// Fast hardware transcendentals: v_exp_f32 (2^x) and v_log_f32 (log2 x).
// exp2f/log2f are precise OCML libcalls (~6 VALU ops) — measured +15 µs of
// VALU time in flash (R9->R12); these are single-instruction.
__device__ __forceinline__ float fexp2(float x) { return __builtin_amdgcn_exp2f(x); }
__device__ __forceinline__ float flog2(float x) { return __builtin_amdgcn_logf(x); }

__device__ __forceinline__ bf16x8 cvt8(float4 a, float4 b) {
  bf16x8 h;
  h[0] = (__bf16)a.x; h[1] = (__bf16)a.y; h[2] = (__bf16)a.z; h[3] = (__bf16)a.w;
  h[4] = (__bf16)b.x; h[5] = (__bf16)b.y; h[6] = (__bf16)b.z; h[7] = (__bf16)b.w;
  return h;
}

__device__ __forceinline__ void gl2lds16(const void* g, void* l) {
  __builtin_amdgcn_global_load_lds(
      (const __attribute__((address_space(1))) u32*)g,
      (__attribute__((address_space(3))) u32*)l, 16, 0, 0);
}

// Stage a 16KB tile (global rows of ROWB bytes at stride 2048B) into LDS,
// linear dest, PRE-SWIZZLED source (byte col ^= (row&7)<<4).
template<int ROWB>
__device__ __forceinline__ void stage_tile(const char* gbase, char* lbase,
                                           int w, int lane) {
  #pragma unroll
  for (int c = 0; c < 2; ++c) {
    const int o = w * 2048 + c * 1024 + lane * 16;
    const int row = o / ROWB;
    const int col = (o % ROWB) ^ ((row & 7) << 4);
    gl2lds16(gbase + (size_t)row * 2048 + col, lbase + w * 2048 + c * 1024);
  }
}

// ---------------------------------------------------------------------------
// Kernel 0: f32 -> bf16 convert, all 7 tensors in one launch.
// ---------------------------------------------------------------------------
__global__ __launch_bounds__(256)
void cvt_all(const float* __restrict__ q, const float* __restrict__ k,
             const float* __restrict__ v, const float* __restrict__ wq,
             const float* __restrict__ wk, const float* __restrict__ wv,
             const float* __restrict__ wo,
             __bf16* __restrict__ qd, __bf16* __restrict__ kd,
             __bf16* __restrict__ vd, __bf16* __restrict__ wqd,
             __bf16* __restrict__ wkd, __bf16* __restrict__ wvd,
             __bf16* __restrict__ wod)
{
  const size_t gid = ((size_t)blockIdx.x * 256 + threadIdx.x) * 8;
  const float* s;
  __bf16* d;
  size_t off;
  if (gid < 8388608)           { s = q;  d = qd;  off = gid; }
  else if (gid < 16777216)     { s = k;  d = kd;  off = gid - 8388608; }
  else if (gid < 25165824)     { s = v;  d = vd;  off = gid - 16777216; }
  else {
    const size_t r = gid - 25165824;
    if (r < 1048576)           { s = wq; d = wqd; off = r; }
    else if (r < 2097152)      { s = wk; d = wkd; off = r - 1048576; }
    else if (r < 3145728)      { s = wv; d = wvd; off = r - 2097152; }
    else                       { s = wo; d = wod; off = r - 3145728; }
  }
  const float4 x0 = *(const float4*)(s + off);
  const float4 x1 = *(const float4*)(s + off + 4);
  *(bf16x8*)(d + off) = cvt8(x0, x1);
}

// ---------------------------------------------------------------------------
// Kernel 1: pure-bf16 projection GEMM (NT), BK=64, 128B LDS rows (flash
// staging/swizzle pattern, 0 bank conflicts). 16 k-steps, one barrier each.
// XCD map: by=(bid&7)+8*((bid>>3)&7).
// OUT_MODE 0: row-major bf16 (scaled). OUT_MODE 1: vpT [B][H][D][S']
// (S 32-block interleave: low5 4g+i(+16 hi) -> 8g+4hi+i).
// ---------------------------------------------------------------------------
template<int OUT_MODE>
__global__ __launch_bounds__(256, 2)
void projb(const __bf16* __restrict__ A, const __bf16* __restrict__ W,
           const float* __restrict__ bias, __bf16* __restrict__ O, float scale)
{
  __shared__ __align__(16) char lds[2][32768];   // [buf][A 16KB | W 16KB]
  const int bid = blockIdx.x;
  const int by = (bid & 7) + 8 * ((bid >> 3) & 7);
  const int bx = bid >> 6;
  const int bm0 = by * 128, bn0 = bx * 128;
  const int tid = threadIdx.x;
  const int lane = tid & 63;
  const int w = tid >> 6;
  const int wm = (w >> 1) * 64, wn = (w & 1) * 64;
  const int lr = lane & 15, g = lane >> 4;
  const int sx = (lr & 7) << 4;
  const int g16 = g * 16;

  f32x4 acc[4][4];
  #pragma unroll
  for (int i = 0; i < 4; ++i)
    #pragma unroll
    for (int j = 0; j < 4; ++j) acc[i][j] = (f32x4){0.f, 0.f, 0.f, 0.f};

  const char* Ab = (const char*)A + (size_t)bm0 * 2048;
  const char* Wb = (const char*)W + (size_t)bn0 * 2048;

  int srow[4], scol[4];
  #pragma unroll
  for (int c = 0; c < 4; ++c) {
    const int o = c * 4096 + tid * 16;
    srow[c] = o >> 7;
    scol[c] = (o & 127) ^ ((srow[c] & 7) << 4);
  }

#define PB_STAGE(buf, kk)                                                     \
  {                                                                           \
    const int kb_ = (kk) * 128;                                               \
    char* lb_ = lds[buf];                                                     \
    _Pragma("unroll")                                                         \
    for (int c = 0; c < 4; ++c) {                                             \
      const int o_ = c * 4096 + tid * 16;                                     \
      gl2lds16(Ab + (size_t)srow[c] * 2048 + kb_ + scol[c], lb_ + o_);        \
      gl2lds16(Wb + (size_t)srow[c] * 2048 + kb_ + scol[c],                   \
               lb_ + 16384 + o_);                                             \
    }                                                                         \
  }

  PB_STAGE(0, 0);
  __syncthreads();

  #pragma unroll 1
  for (int kk = 0; kk < 16; ++kk) {
    const int cur = kk & 1;
    if (kk < 15) PB_STAGE(cur ^ 1, kk + 1);
    const char* la = lds[cur];
    const char* lw = lds[cur] + 16384;
    #pragma unroll
    for (int kh = 0; kh < 2; ++kh) {
      const int ko = (kh * 64 + g16) ^ sx;
      bf16x8 aF[4], bF[4];
      #pragma unroll
      for (int t = 0; t < 4; ++t) {
        aF[t] = *(const bf16x8*)(la + (wm + t * 16 + lr) * 128 + ko);
        bF[t] = *(const bf16x8*)(lw + (wn + t * 16 + lr) * 128 + ko);
      }
      #pragma unroll
      for (int mt = 0; mt < 4; ++mt)
        #pragma unroll
        for (int nt = 0; nt < 4; ++nt)
          acc[mt][nt] = mfma16(aF[mt], bF[nt], acc[mt][nt]);
    }
    __syncthreads();
  }
#undef PB_STAGE

  const int col = lane & 15;
  const int rb = (lane >> 4) * 4;
  #pragma unroll
  for (int nt = 0; nt < 4; ++nt) {
    const int n = bn0 + wn + nt * 16 + col;
    const float bvv = bias[n];
    #pragma unroll
    for (int mt = 0; mt < 4; ++mt) {
      #pragma unroll
      for (int i = 0; i < 4; ++i) {
        const int m = bm0 + wm + mt * 16 + rb + i;
        const float v = (acc[mt][nt][i] + bvv) * scale;
        if constexpr (OUT_MODE == 0) {
          O[(size_t)m * 1024 + n] = (__bf16)v;
        } else {
          const int bb = m >> 10, s = m & 1023, hh = n >> 6, dd = n & 63;
          const int low = s & 31;
          const int si = (s & ~31) | (((low >> 2) & 3) << 3) |
                         (((low >> 4) & 1) << 2) | (low & 3);
          O[((size_t)((bb * 16 + hh) * 64 + dd)) * 1024 + si] = (__bf16)v;
        }
      }
    }
  }
}

// ---------------------------------------------------------------------------
// Kernel 3: pure-bf16 out projection, f32 out. Same structure as projb.
// ---------------------------------------------------------------------------
__global__ __launch_bounds__(256, 2)
void outb(const __bf16* __restrict__ A, const __bf16* __restrict__ W,
          const float* __restrict__ bias, float* __restrict__ O)
{
  __shared__ __align__(16) char lds[2][32768];
  const int bid = blockIdx.x;
  const int by = (bid & 7) + 8 * ((bid >> 3) & 7);
  const int bx = bid >> 6;
  const int bm0 = by * 128, bn0 = bx * 128;
  const int tid = threadIdx.x;
  const int lane = tid & 63;
  const int w = tid >> 6;
  const int wm = (w >> 1) * 64, wn = (w & 1) * 64;
  const int lr = lane & 15, g = lane >> 4;
  const int sx = (lr & 7) << 4;
  const int g16 = g * 16;

  f32x4 acc[4][4];
  #pragma unroll
  for (int i = 0; i < 4; ++i)
    #pragma unroll
    for (int j = 0; j < 4; ++j) acc[i][j] = (f32x4){0.f, 0.f, 0.f, 0.f};

  const char* Ab = (const char*)A + (size_t)bm0 * 2048;
  const char* Wb = (const char*)W + (size_t)bn0 * 2048;

  int srow[4], scol[4];
  #pragma unroll
  for (int c = 0; c < 4; ++c) {
    const int o = c * 4096 + tid * 16;
    srow[c] = o >> 7;
    scol[c] = (o & 127) ^ ((srow[c] & 7) << 4);
  }

#define OB_STAGE(buf, kk)                                                     \
  {                                                                           \
    const int kb_ = (kk) * 128;                                               \
    char* lb_ = lds[buf];                                                     \
    _Pragma("unroll")                                                         \
    for (int c = 0; c < 4; ++c) {                                             \
      const int o_ = c * 4096 + tid * 16;                                     \
      gl2lds16(Ab + (size_t)srow[c] * 2048 + kb_ + scol[c], lb_ + o_);        \
      gl2lds16(Wb + (size_t)srow[c] * 2048 + kb_ + scol[c],                   \
               lb_ + 16384 + o_);                                             \
    }                                                                         \
  }

  OB_STAGE(0, 0);
  __syncthreads();

  #pragma unroll 1
  for (int kk = 0; kk < 16; ++kk) {
    const int cur = kk & 1;
    if (kk < 15) OB_STAGE(cur ^ 1, kk + 1);
    const char* la = lds[cur];
    const char* lw = lds[cur] + 16384;
    #pragma unroll
    for (int kh = 0; kh < 2; ++kh) {
      const int ko = (kh * 64 + g16) ^ sx;
      bf16x8 aF[4], bF[4];
      #pragma unroll
      for (int t = 0; t < 4; ++t) {
        aF[t] = *(const bf16x8*)(la + (wm + t * 16 + lr) * 128 + ko);
        bF[t] = *(const bf16x8*)(lw + (wn + t * 16 + lr) * 128 + ko);
      }
      #pragma unroll
      for (int mt = 0; mt < 4; ++mt)
        #pragma unroll
        for (int nt = 0; nt < 4; ++nt)
          acc[mt][nt] = mfma16(aF[mt], bF[nt], acc[mt][nt]);
    }
    __syncthreads();
  }
#undef OB_STAGE

  const int col = lane & 15;
  const int rb = (lane >> 4) * 4;
  #pragma unroll
  for (int nt = 0; nt < 4; ++nt) {
    const int n = bn0 + wn + nt * 16 + col;
    const float bvv = bias[n];
    #pragma unroll
    for (int mt = 0; mt < 4; ++mt) {
      #pragma unroll
      for (int i = 0; i < 4; ++i) {
        const int m = bm0 + wm + mt * 16 + rb + i;
        O[(size_t)m * 1024 + n] = acc[mt][nt][i] + bvv;
      }
    }
  }
}

// ---------------------------------------------------------------------------
// Fallback-path f32-staged GEMMs (R9 structure).
// ---------------------------------------------------------------------------
template<int OUT_MODE>
__global__ __launch_bounds__(256, 2)
void proj_gemm(const float* __restrict__ A, const float* __restrict__ W,
               const float* __restrict__ bias, __bf16* __restrict__ O, float scale)
{
  __shared__ __align__(16) char lds[2][32768];
  const int bid = blockIdx.x;
  const int by = (bid & 7) + 8 * ((bid >> 3) & 7);
  const int bx = bid >> 6;
  const int bm0 = by * 128, bn0 = bx * 128;
  const int tid = threadIdx.x;
  const int lane = tid & 63;
  const int w = tid >> 6;
  const int wm = (w >> 1) * 64, wn = (w & 1) * 64;
  const int lr = lane & 15, g = lane >> 4;
  const int sx = (lr & 7) << 4;

  f32x4 acc[4][4];
  #pragma unroll
  for (int i = 0; i < 4; ++i)
    #pragma unroll
    for (int j = 0; j < 4; ++j) acc[i][j] = (f32x4){0.f, 0.f, 0.f, 0.f};

  const char* Ab = (const char*)A + (size_t)bm0 * 4096;
  const char* Wb = (const char*)W + (size_t)bn0 * 4096;

  int srow[4], scol[4];
  #pragma unroll
  for (int c = 0; c < 4; ++c) {
    const int o = w * 4096 + c * 1024 + lane * 16;
    srow[c] = o >> 7;
    scol[c] = (o & 127) ^ ((srow[c] & 7) << 4);
  }

#define PJ_STAGE(buf, kk)                                                     \
  {                                                                           \
    const int kb_ = (kk) * 128;                                               \
    char* lb_ = lds[buf];                                                     \
    _Pragma("unroll")                                                         \
    for (int c = 0; c < 4; ++c) {                                             \
      gl2lds16(Ab + (size_t)srow[c] * 4096 + kb_ + scol[c],                   \
               lb_ + w * 4096 + c * 1024);                                    \
      gl2lds16(Wb + (size_t)srow[c] * 4096 + kb_ + scol[c],                   \
               lb_ + 16384 + w * 4096 + c * 1024);                            \
    }                                                                         \
  }

  PJ_STAGE(0, 0);
  __syncthreads();

  #pragma unroll 1
  for (int kk = 0; kk < 32; ++kk) {
    const int cur = kk & 1;
    if (kk < 31) PJ_STAGE(cur ^ 1, kk + 1);
    const char* la = lds[cur];
    const char* lw = lds[cur] + 16384;
    bf16x8 aF[4], bF[4];
    #pragma unroll
    for (int t = 0; t < 4; ++t) {
      const int ra = (wm + t * 16 + lr) << 7;
      const float4 a0 = *(const float4*)(la + ra + ((g * 32) ^ sx));
      const float4 a1 = *(const float4*)(la + ra + ((g * 32 + 16) ^ sx));
      aF[t] = cvt8(a0, a1);
      const int rb = (wn + t * 16 + lr) << 7;
      const float4 b0 = *(const float4*)(lw + rb + ((g * 32) ^ sx));
      const float4 b1 = *(const float4*)(lw + rb + ((g * 32 + 16) ^ sx));
      bF[t] = cvt8(b0, b1);
    }
    #pragma unroll
    for (int mt = 0; mt < 4; ++mt)
      #pragma unroll
      for (int nt = 0; nt < 4; ++nt)
        acc[mt][nt] = mfma16(aF[mt], bF[nt], acc[mt][nt]);
    __syncthreads();
  }
#undef PJ_STAGE

  const int col = lane & 15;
  const int rb = (lane >> 4) * 4;
  #pragma unroll
  for (int nt = 0; nt < 4; ++nt) {
    const int n = bn0 + wn + nt * 16 + col;
    const float bvv = bias[n];
    #pragma unroll
    for (int mt = 0; mt < 4; ++mt) {
      #pragma unroll
      for (int i = 0; i < 4; ++i) {
        const int m = bm0 + wm + mt * 16 + rb + i;
        const float v = (acc[mt][nt][i] + bvv) * scale;
        if constexpr (OUT_MODE == 0) {
          O[(size_t)m * 1024 + n] = (__bf16)v;
        } else {
          const int bb = m >> 10, s = m & 1023, hh = n >> 6, dd = n & 63;
          const int low = s & 31;
          const int si = (s & ~31) | (((low >> 2) & 3) << 3) |
                         (((low >> 4) & 1) << 2) | (low & 3);
          O[((size_t)((bb * 16 + hh) * 64 + dd)) * 1024 + si] = (__bf16)v;
        }
      }
    }
  }
}

__global__ __launch_bounds__(256, 2)
void out_gemm(const __bf16* __restrict__ A, const float* __restrict__ W,
              const float* __restrict__ bias, float* __restrict__ O)
{
  __shared__ __align__(16) char lds[2][24576];
  const int bid = blockIdx.x;
  const int by = (bid & 7) + 8 * ((bid >> 3) & 7);
  const int bx = bid >> 6;
  const int bm0 = by * 128, bn0 = bx * 128;
  const int tid = threadIdx.x;
  const int lane = tid & 63;
  const int w = tid >> 6;
  const int wm = (w >> 1) * 64, wn = (w & 1) * 64;
  const int lr = lane & 15, g = lane >> 4;
  const int sxA = (lr & 3) << 4;
  const int sxW = (lr & 7) << 4;

  f32x4 acc[4][4];
  #pragma unroll
  for (int i = 0; i < 4; ++i)
    #pragma unroll
    for (int j = 0; j < 4; ++j) acc[i][j] = (f32x4){0.f, 0.f, 0.f, 0.f};

  const char* Ab = (const char*)A + (size_t)bm0 * 2048;
  const char* Wb = (const char*)W + (size_t)bn0 * 4096;

  int arow[2], acol[2], wrow[4], wcol[4];
  #pragma unroll
  for (int c = 0; c < 2; ++c) {
    const int o = w * 2048 + c * 1024 + lane * 16;
    arow[c] = o >> 6;
    acol[c] = (o & 63) ^ ((arow[c] & 3) << 4);
  }
  #pragma unroll
  for (int c = 0; c < 4; ++c) {
    const int o = w * 4096 + c * 1024 + lane * 16;
    wrow[c] = o >> 7;
    wcol[c] = (o & 127) ^ ((wrow[c] & 7) << 4);
  }

#define OG_STAGE(buf, kk)                                                     \
  {                                                                           \
    char* lb_ = lds[buf];                                                     \
    _Pragma("unroll")                                                         \
    for (int c = 0; c < 2; ++c)                                               \
      gl2lds16(Ab + (size_t)arow[c] * 2048 + (kk) * 64 + acol[c],             \
               lb_ + w * 2048 + c * 1024);                                    \
    _Pragma("unroll")                                                         \
    for (int c = 0; c < 4; ++c)                                               \
      gl2lds16(Wb + (size_t)wrow[c] * 4096 + (kk) * 128 + wcol[c],            \
               lb_ + 8192 + w * 4096 + c * 1024);                             \
  }

  OG_STAGE(0, 0);
  __syncthreads();

  #pragma unroll 1
  for (int kk = 0; kk < 32; ++kk) {
    const int cur = kk & 1;
    if (kk < 31) OG_STAGE(cur ^ 1, kk + 1);
    const char* la = lds[cur];
    const char* lw = lds[cur] + 8192;
    bf16x8 aF[4], bF[4];
    #pragma unroll
    for (int t = 0; t < 4; ++t) {
      const int ra = (wm + t * 16 + lr) << 6;
      aF[t] = *(const bf16x8*)(la + ra + ((g * 16) ^ sxA));
      const int rb = (wn + t * 16 + lr) << 7;
      const float4 b0 = *(const float4*)(lw + rb + ((g * 32) ^ sxW));
      const float4 b1 = *(const float4*)(lw + rb + ((g * 32 + 16) ^ sxW));
      bF[t] = cvt8(b0, b1);
    }
    #pragma unroll
    for (int mt = 0; mt < 4; ++mt)
      #pragma unroll
      for (int nt = 0; nt < 4; ++nt)
        acc[mt][nt] = mfma16(aF[mt], bF[nt], acc[mt][nt]);
    __syncthreads();
  }
#undef OG_STAGE

  const int col = lane & 15;
  const int rb = (lane >> 4) * 4;
  #pragma unroll
  for (int nt = 0; nt < 4; ++nt) {
    const int n = bn0 + wn + nt * 16 + col;
    const float bvv = bias[n];
    #pragma unroll
    for (int mt = 0; mt < 4; ++mt) {
      #pragma unroll
      for (int i = 0; i < 4; ++i) {
        const int m = bm0 + wm + mt * 16 + rb + i;
        O[(size_t)m * 1024 + n] = acc[mt][nt][i] + bvv;
      }
    }
  }
}

// ---------------------------------------------------------------------------
// Kernel 2a: flash attention — R8 structure (128-s-tile, K16KB+V16KB dbuf,
// one barrier per tile), fused exp/pack, log2-domain softmax with RAW
// v_exp_f32 / v_log_f32 (fexp2/flog2), THR=11.5 (e^8 window).
// ---------------------------------------------------------------------------
__global__ __launch_bounds__(512, 4)
void flash_attn2(const __bf16* __restrict__ qp, const __bf16* __restrict__ kp,
                 const __bf16* __restrict__ vpT, __bf16* __restrict__ rep,
                 float* __restrict__ cbuf)
{
  __shared__ __align__(16) char lds[2][32768];  // [buf][K 16KB | V 16KB]

  const int bid = blockIdx.x;
  const int b = bid & 7;
  const int rest = bid >> 3;
  const int h = rest & 15;
  const int tb = rest >> 4;
  const int tid = threadIdx.x;
  const int w = tid >> 6;
  const int lane = tid & 63;
  const int lr = lane & 15;
  const int g = lane >> 4;
  const int t0 = tb * 128 + w * 16;
  const int sx = (lr & 7) << 4;
  const int g16 = g * 16;

  const __bf16* qb = qp + (size_t)(b * 1024 + t0 + lr) * 1024 + h * 64 + g * 8;
  const bf16x8 bF0 = *(const bf16x8*)qb;
  const bf16x8 bF1 = *(const bf16x8*)(qb + 32);

  const char* kgb = (const char*)kp + ((size_t)(b * 1024) * 1024 + h * 64) * 2;
  const char* vgb = (const char*)vpT + ((size_t)((b * 16 + h) * 64) * 1024) * 2;

  f32x4 o0 = {0.f,0.f,0.f,0.f}, o1 = {0.f,0.f,0.f,0.f};
  f32x4 o2 = {0.f,0.f,0.f,0.f}, o3 = {0.f,0.f,0.f,0.f};
  float m = -3.0e38f, l = 0.f;

  stage_tile<128>(kgb, lds[0], w, lane);
  stage_tile<256>(vgb, lds[0] + 16384, w, lane);
  __syncthreads();

  #pragma unroll 1
  for (int st = 0; st < 8; ++st) {
    const char* kb = lds[st & 1];
    const char* vb = lds[st & 1] + 16384;
    if (st < 7) {
      stage_tile<128>(kgb + (size_t)(st + 1) * 128 * 2048, lds[(st & 1) ^ 1], w, lane);
      stage_tile<256>(vgb + (size_t)(st + 1) * 256, lds[(st & 1) ^ 1] + 16384, w, lane);
    }

    f32x4 p[8];
    #pragma unroll
    for (int j = 0; j < 8; ++j) {
      const bf16x8 k0 = *(const bf16x8*)(kb + j * 2048 + lr * 128 + (g16 ^ sx));
      const bf16x8 k1 = *(const bf16x8*)(kb + j * 2048 + lr * 128 + ((64 + g16) ^ sx));
      f32x4 d = {0.f, 0.f, 0.f, 0.f};
      d = mfma16(k0, bF0, d);
      d = mfma16(k1, bF1, d);
      p[j] = d;
    }

    f32x4 m4 = p[0];
    #pragma unroll
    for (int j = 1; j < 8; ++j)
      #pragma unroll
      for (int i = 0; i < 4; ++i) m4[i] = fmaxf(m4[i], p[j][i]);
    const float pm = fmaxf(fmaxf(m4[0], m4[1]), fmaxf(m4[2], m4[3]));
    if (!__all(pm - m <= 11.5f)) {
      float mt = pm;
      mt = fmaxf(mt, __shfl_xor(mt, 16));
      mt = fmaxf(mt, __shfl_xor(mt, 32));
      const float mnew = fmaxf(m, mt);
      const float r = fexp2(m - mnew);
      m = mnew;
      l *= r;
      f32x4 rr;
      rr[0] = __shfl(r, g * 4 + 0);
      rr[1] = __shfl(r, g * 4 + 1);
      rr[2] = __shfl(r, g * 4 + 2);
      rr[3] = __shfl(r, g * 4 + 3);
      #pragma unroll
      for (int i = 0; i < 4; ++i) {
        o0[i] *= rr[i]; o1[i] *= rr[i]; o2[i] *= rr[i]; o3[i] *= rr[i];
      }
    }

    bf16x8 av[4];
    f32x4 s4 = {0.f, 0.f, 0.f, 0.f};
    #pragma unroll
    for (int j = 0; j < 8; ++j)
      #pragma unroll
      for (int i = 0; i < 4; ++i) {
        const float e = fexp2(p[j][i] - m);
        s4[i] += e;
        av[j >> 1][(j & 1) * 4 + i] = (__bf16)e;
      }
    l += (s4[0] + s4[1]) + (s4[2] + s4[3]);

    #pragma unroll
    for (int m2 = 0; m2 < 4; ++m2) {
      const int vo = lr * 256 + ((m2 * 64 + g16) ^ sx);
      o0 = mfma16(av[m2], *(const bf16x8*)(vb + vo), o0);
      o1 = mfma16(av[m2], *(const bf16x8*)(vb + 4096 + vo), o1);
      o2 = mfma16(av[m2], *(const bf16x8*)(vb + 8192 + vo), o2);
      o3 = mfma16(av[m2], *(const bf16x8*)(vb + 12288 + vo), o3);
    }
    __syncthreads();
  }

  float lt = l + __shfl_xor(l, 16);
  lt += __shfl_xor(lt, 32);

  if (lane < 16) cbuf[(size_t)(b * 16 + h) * 1024 + t0 + lr] = m + flog2(lt);

  const float inv = 1.f / lt;
  f32x4 iv;
  iv[0] = __shfl(inv, g * 4 + 0);
  iv[1] = __shfl(inv, g * 4 + 1);
  iv[2] = __shfl(inv, g * 4 + 2);
  iv[3] = __shfl(inv, g * 4 + 3);
  __bf16* rbase = rep + (size_t)(b * 1024 + t0) * 1024 + h * 64 + lr;
  #pragma unroll
  for (int i = 0; i < 4; ++i) {
    const size_t ro = (size_t)(g * 4 + i) * 1024;
    rbase[ro] = (__bf16)(o0[i] * iv[i]);
    rbase[ro + 16] = (__bf16)(o1[i] * iv[i]);
    rbase[ro + 32] = (__bf16)(o2[i] * iv[i]);
    rbase[ro + 48] = (__bf16)(o3[i] * iv[i]);
  }
}

// ---------------------------------------------------------------------------
// Kernel 2b: attn_max via LSE identity, log2 domain: max_h 2^(s2_h - c_h).
// ---------------------------------------------------------------------------
__global__ __launch_bounds__(512, 4)
void amax_kernel2(const __bf16* __restrict__ qp, const __bf16* __restrict__ kp,
                  const float* __restrict__ cbuf, float* __restrict__ amax_out)
{
  __shared__ __align__(16) char lds[2][16384];

  const int bid = blockIdx.x;
  const int b = bid & 7;
  const int rest = bid >> 3;
  const int sp = rest & 7;
  const int tb = rest >> 3;
  const int tid = threadIdx.x;
  const int w = tid >> 6;
  const int lane = tid & 63;
  const int lr = lane & 15;
  const int g = lane >> 4;
  const int t0 = tb * 128 + w * 16;
  const int s0 = sp * 128;
  const int sx = (lr & 7) << 4;
  const int g16 = g * 16;

  f32x4 am[8];
  #pragma unroll
  for (int j = 0; j < 8; ++j)
    am[j] = (f32x4){-3.0e38f, -3.0e38f, -3.0e38f, -3.0e38f};

  const char* kgb = (const char*)kp + ((size_t)(b * 1024 + s0) * 1024) * 2;
  const size_t qrow = (size_t)(b * 1024 + t0 + lr) * 1024 + g * 8;

  stage_tile<128>(kgb, lds[0], w, lane);
  __syncthreads();

  #pragma unroll 1
  for (int h = 0; h < 16; ++h) {
    const char* kb = lds[h & 1];
    if (h < 15) stage_tile<128>(kgb + (h + 1) * 128, lds[(h & 1) ^ 1], w, lane);

    const __bf16* qbh = qp + qrow + h * 64;
    const bf16x8 bF0 = *(const bf16x8*)qbh;
    const bf16x8 bF1 = *(const bf16x8*)(qbh + 32);
    const float ch = cbuf[(size_t)(b * 16 + h) * 1024 + t0 + lr];

    #pragma unroll
    for (int j = 0; j < 8; ++j) {
      const bf16x8 k0 = *(const bf16x8*)(kb + j * 2048 + lr * 128 + (g16 ^ sx));
      const bf16x8 k1 = *(const bf16x8*)(kb + j * 2048 + lr * 128 + ((64 + g16) ^ sx));
      f32x4 d = {0.f, 0.f, 0.f, 0.f};
      d = mfma16(k0, bF0, d);
      d = mfma16(k1, bF1, d);
      #pragma unroll
      for (int i = 0; i < 4; ++i) am[j][i] = fmaxf(am[j][i], d[i] - ch);
    }
    __syncthreads();
  }

  const size_t arow = (size_t)(b * 1024 + t0 + lr) * 1024;
  #pragma unroll
  for (int j = 0; j < 8; ++j) {
    f32x4 v;
    #pragma unroll
    for (int i = 0; i < 4; ++i) v[i] = fexp2(am[j][i]);
    *(f32x4*)&amax_out[arow + s0 + j * 16 + g * 4] = v;
  }
}

// ---------------------------------------------------------------------------
// Fallback attention (ws too small for cbuf). log2 domain, fast exp2.
// ---------------------------------------------------------------------------
__global__ __launch_bounds__(512, 4)
void attn_kernel(const __bf16* __restrict__ qp, const __bf16* __restrict__ kp,
                 const __bf16* __restrict__ vpT, __bf16* __restrict__ rep,
                 float* __restrict__ amax_out)
{
  __shared__ float2 red[16][8];
  __shared__ float invb[16];
  __shared__ __align__(16) float ob[2][8 * 64 * 17];

  const int bid = blockIdx.x;
  const int b = bid & 7;
  const int t0 = (bid >> 3) * 16;
  const int tid = threadIdx.x;
  const int lane = tid & 63;
  const int w = tid >> 6;
  const int lr = lane & 15;
  const int g = lane >> 4;

  bf16x4 am4[8];
  #pragma unroll
  for (int j = 0; j < 8; ++j)
    #pragma unroll
    for (int i = 0; i < 4; ++i) am4[j][i] = (__bf16)0.f;

  const size_t qrow = (size_t)(b * 1024 + t0 + lr) * 1024;
  const int et = tid >> 5;
  const int ed = tid & 31;

  for (int h = 0; h < 16; ++h) {
    const __bf16* qb = qp + qrow + h * 64 + g * 8;
    const bf16x8 bF0 = *(const bf16x8*)qb;
    const bf16x8 bF1 = *(const bf16x8*)(qb + 32);

    f32x4 p[8];
    #pragma unroll
    for (int j = 0; j < 8; ++j) {
      const int s0 = w * 128 + j * 16;
      const __bf16* kb = kp + (size_t)(b * 1024 + s0 + lr) * 1024 + h * 64 + g * 8;
      f32x4 d = {0.f, 0.f, 0.f, 0.f};
      d = mfma16(*(const bf16x8*)kb, bF0, d);
      d = mfma16(*(const bf16x8*)(kb + 32), bF1, d);
      p[j] = d;
    }

    f32x4 m4 = p[0];
    #pragma unroll
    for (int j = 1; j < 8; ++j)
      #pragma unroll
      for (int i = 0; i < 4; ++i) m4[i] = fmaxf(m4[i], p[j][i]);
    float mm = fmaxf(fmaxf(m4[0], m4[1]), fmaxf(m4[2], m4[3]));
    mm = fmaxf(mm, __shfl_xor(mm, 16));
    mm = fmaxf(mm, __shfl_xor(mm, 32));

    f32x4 s4 = {0.f, 0.f, 0.f, 0.f};
    #pragma unroll
    for (int j = 0; j < 8; ++j)
      #pragma unroll
      for (int i = 0; i < 4; ++i) {
        const float e = fexp2(p[j][i] - mm);
        p[j][i] = e;
        s4[i] += e;
      }
    float ss = (s4[0] + s4[1]) + (s4[2] + s4[3]);
    ss += __shfl_xor(ss, 16);
    ss += __shfl_xor(ss, 32);
    if (lane < 16) red[lr][w] = make_float2(mm, ss);
    __syncthreads();

    float m = red[lr][0].x;
    #pragma unroll
    for (int k = 1; k < 8; ++k) m = fmaxf(m, red[lr][k].x);
    float sum = 0.f;
    #pragma unroll
    for (int k = 0; k < 8; ++k) sum += red[lr][k].y * fexp2(red[lr][k].x - m);
    const float fw = fexp2(mm - m);
    const float inv = 1.f / sum;
    if (w == 0 && lane < 16) invb[lr] = inv;
    const float c = fw * inv;

    #pragma unroll
    for (int j = 0; j < 8; ++j)
      #pragma unroll
      for (int i = 0; i < 4; ++i) {
        const float pn = p[j][i] * c;
        const float o = (float)am4[j][i];
        am4[j][i] = (__bf16)fmaxf(o, pn);
      }

    f32x4 po[4];
    #pragma unroll
    for (int dc = 0; dc < 4; ++dc) po[dc] = (f32x4){0.f, 0.f, 0.f, 0.f};
    const __bf16* vb0 = vpT + ((size_t)((b * 16 + h) * 64) + lr) * 1024 + w * 128;
    #pragma unroll
    for (int m2 = 0; m2 < 4; ++m2) {
      bf16x8 av;
      #pragma unroll
      for (int i = 0; i < 4; ++i) {
        av[i] = (__bf16)(p[2 * m2][i] * fw);
        av[4 + i] = (__bf16)(p[2 * m2 + 1][i] * fw);
      }
      const int so = m2 * 32 + g * 8;
      #pragma unroll
      for (int dc = 0; dc < 4; ++dc) {
        const bf16x8 bv = *(const bf16x8*)(vb0 + (size_t)(dc * 16) * 1024 + so);
        po[dc] = mfma16(av, bv, po[dc]);
      }
    }

    float* obh = ob[h & 1];
    #pragma unroll
    for (int dc = 0; dc < 4; ++dc)
      *(f32x4*)&obh[(w * 64 + dc * 16 + lr) * 17 + g * 4] = po[dc];
    __syncthreads();

    float a0 = 0.f, a1 = 0.f;
    #pragma unroll
    for (int w2 = 0; w2 < 8; ++w2) {
      a0 += obh[(w2 * 64 + ed) * 17 + et];
      a1 += obh[(w2 * 64 + 32 + ed) * 17 + et];
    }
    const float ivv = invb[et];
    __bf16* rrow = rep + (size_t)(b * 1024 + t0 + et) * 1024 + h * 64;
    rrow[ed] = (__bf16)(a0 * ivv);
    rrow[32 + ed] = (__bf16)(a1 * ivv);
  }

  const size_t arow = (size_t)(b * 1024 + t0 + lr) * 1024;
  #pragma unroll
  for (int j = 0; j < 8; ++j) {
    f32x4 v;
    #pragma unroll
    for (int i = 0; i < 4; ++i) v[i] = (float)am4[j][i];
    *(f32x4*)&amax_out[arow + w * 128 + j * 16 + g * 4] = v;
  }
}

// ---------------------------------------------------------------------------
extern "C" void kernel_launch(void* const* d_in, const int* in_sizes, int n_in,
                              void* d_out, int out_size, void* d_ws, size_t ws_size,
                              hipStream_t stream)
{
  const float* query = (const float*)d_in[0];
  const float* key   = (const float*)d_in[1];
  const float* value = (const float*)d_in[2];
  const float* Wq = (const float*)d_in[3];
  const float* bq = (const float*)d_in[4];
  const float* Wk = (const float*)d_in[5];
  const float* bk = (const float*)d_in[6];
  const float* Wv = (const float*)d_in[7];
  const float* bv = (const float*)d_in[8];
  const float* Wo = (const float*)d_in[9];
  const float* bo = (const float*)d_in[10];

  float* out = (float*)d_out;
  float* amax_out = out + (size_t)8 * 1024 * 1024;

  char* wsb = (char*)d_ws;
  __bf16* qp  = (__bf16*)wsb;                                 // 16MB
  __bf16* kp  = (__bf16*)(wsb + ((size_t)16 << 20));          // 16MB
  __bf16* vpT = (__bf16*)(wsb + ((size_t)32 << 20));          // 16MB [B][H][D][S']

  // q scale: D^-0.5 * log2(e) -> scores in log2 domain for exp2-based softmax
  const float qscale = 0.125f * 1.44269504089f;

  if (ws_size >= ((size_t)105 << 20)) {
    // ---- full bf16 path: convert once, pure-bf16 GEMMs ----
    __bf16* qin = (__bf16*)(wsb + ((size_t)48 << 20));        // 16MB; reused as rep
    __bf16* kin = (__bf16*)(wsb + ((size_t)64 << 20));        // 16MB
    __bf16* vin = (__bf16*)(wsb + ((size_t)80 << 20));        // 16MB
    __bf16* Wqb = (__bf16*)(wsb + ((size_t)96 << 20));        // 2MB
    __bf16* Wkb = (__bf16*)(wsb + ((size_t)98 << 20));        // 2MB
    __bf16* Wvb = (__bf16*)(wsb + ((size_t)100 << 20));       // 2MB
    __bf16* Wob = (__bf16*)(wsb + ((size_t)102 << 20));       // 2MB
    float* cbuf = (float*)(wsb + ((size_t)104 << 20));        // 512KB
    __bf16* rep = qin;  // qin dead after proj q

    cvt_all<<<14336, 256, 0, stream>>>(query, key, value, Wq, Wk, Wv, Wo,
                                       qin, kin, vin, Wqb, Wkb, Wvb, Wob);
    projb<0><<<512, 256, 0, stream>>>(qin, Wqb, bq, qp, qscale);
    projb<0><<<512, 256, 0, stream>>>(kin, Wkb, bk, kp, 1.0f);
    projb<1><<<512, 256, 0, stream>>>(vin, Wvb, bv, vpT, 1.0f);
    flash_attn2<<<1024, 512, 0, stream>>>(qp, kp, vpT, rep, cbuf);
    amax_kernel2<<<512, 512, 0, stream>>>(qp, kp, cbuf, amax_out);
    outb<<<512, 256, 0, stream>>>(rep, Wob, bo, out);
  } else if (ws_size >= ((size_t)65 << 20)) {
    // ---- R9 f32-staged path ----
    __bf16* rep = (__bf16*)(wsb + ((size_t)48 << 20));
    float* cbuf = (float*)(wsb + ((size_t)64 << 20));
    proj_gemm<0><<<512, 256, 0, stream>>>(query, Wq, bq, qp, qscale);
    proj_gemm<0><<<512, 256, 0, stream>>>(key,   Wk, bk, kp, 1.0f);
    proj_gemm<1><<<512, 256, 0, stream>>>(value, Wv, bv, vpT, 1.0f);
    flash_attn2<<<1024, 512, 0, stream>>>(qp, kp, vpT, rep, cbuf);
    amax_kernel2<<<512, 512, 0, stream>>>(qp, kp, cbuf, amax_out);
    out_gemm<<<512, 256, 0, stream>>>(rep, Wo, bo, out);
  } else {
    __bf16* rep = (ws_size >= ((size_t)64 << 20)) ? (__bf16*)(wsb + ((size_t)48 << 20)) : qp;
    proj_gemm<0><<<512, 256, 0, stream>>>(query, Wq, bq, qp, qscale);
    proj_gemm<0><<<512, 256, 0, stream>>>(key,   Wk, bk, kp, 1.0f);
    proj_gemm<1><<<512, 256, 0, stream>>>(value, Wv, bv, vpT, 1.0f);
    attn_kernel<<<512, 512, 0, stream>>>(qp, kp, vpT, rep, amax_out);
    out_gemm<<<512, 256, 0, stream>>>(rep, Wo, bo, out);
  }
}